// Round 2
// 717.457 us; speedup vs baseline: 1.0332x; 1.0332x over previous
//
#include <hip/hip_runtime.h>
#include <math.h>

// Problem constants: b=4, c=256, heads=8, c/head=32, h=w=128, n=16384, cr=16
#define NFFT 16384
static constexpr size_t NP = 16777216; // one plane = 1024 * 16384 floats

typedef short bf16x8 __attribute__((ext_vector_type(8)));
typedef float f32x4  __attribute__((ext_vector_type(4)));
typedef __fp16 h16x2 __attribute__((ext_vector_type(2)));

// ---------- helpers ----------
__device__ __forceinline__ void sincos_rev(float rv, float& sn, float& cs){
    sn = __builtin_amdgcn_sinf(rv);   // sin(2*pi*rv)
    cs = __builtin_amdgcn_cosf(rv);
}
__device__ __forceinline__ int rev7(int v){ return (int)(__brev((unsigned)v) >> 25); }

__device__ __forceinline__ unsigned f2bf(float f){
    unsigned u = __float_as_uint(f);
    return (u + 0x7FFFu + ((u >> 16) & 1u)) >> 16;   // round-to-nearest-even
}
__device__ __forceinline__ float bf2f(unsigned h){ return __uint_as_float(h << 16); }
// pack fp32 -> (bf16 hi | bf16 lo) in one u32, stored via float bit-pattern
__device__ __forceinline__ unsigned packsplit(float v){
    unsigned h = f2bf(v);
    float r = v - bf2f(h);
    unsigned l = f2bf(r);
    return (h << 16) | l;
}

// fp16x2 pack/unpack for the LDS transpose plane (single u32 per complex value).
// v_cvt_pkrtz_f16_f32 = 1 instr; precision: rel err <= 2^-10, mid-FFT values are
// O(10) max -> final output contribution < 1e-3 abs (threshold margin ~4x).
union HU2 { h16x2 h; unsigned u; };
__device__ __forceinline__ unsigned packh(float a, float b){
    HU2 z; z.h = __builtin_amdgcn_cvt_pkrtz(a, b); return z.u;
}
__device__ __forceinline__ void unpackh(unsigned u, float& a, float& b){
    HU2 z; z.u = u; a = (float)z.h.x; b = (float)z.h.y;
}

// ---------- sign/identity-folded per-lane twiddles ----------
// DIF (forward): per stage, down-lane: w'=(1,0), sg=+1; up-lane: w'=(cos, -sin), sg=-1.
struct TwF { float cw[6], sw[6], sg[6], c6, s6; };
__device__ __forceinline__ void make_twf(TwF& t){
    const int l = threadIdx.x & 63;
    #pragma unroll
    for (int lg = 0; lg < 6; ++lg){
        int m = 1 << lg;
        bool up = (l & m) != 0;
        int e = (l & (m-1)) * (64 >> lg);
        float sn, cs; sincos_rev((float)e * 0.0078125f, sn, cs);
        t.cw[lg] = up ? cs : 1.f;
        t.sw[lg] = up ? -sn : 0.f;
        t.sg[lg] = up ? -1.f : 1.f;
    }
    sincos_rev((float)l * 0.0078125f, t.s6, t.c6);
}
// DIT (inverse): both lanes multiply by w=(cos,sin); up-lane sign-negated: w'=-w.
struct TwI { float cw[6], sw[6], c6, s6; };
__device__ __forceinline__ void make_twi(TwI& t){
    const int l = threadIdx.x & 63;
    #pragma unroll
    for (int lg = 0; lg < 6; ++lg){
        int m = 1 << lg;
        bool up = (l & m) != 0;
        int e = (l & (m-1)) * (64 >> lg);
        float sn, cs; sincos_rev((float)e * 0.0078125f, sn, cs);
        t.cw[lg] = up ? -cs : cs;
        t.sw[lg] = up ? -sn : sn;
    }
    sincos_rev((float)l * 0.0078125f, t.s6, t.c6);
}

// DIF forward: natural in, slot j holds X[rev7(j)] out. W = e^{-2pi i/128}
__device__ __forceinline__ void dif128t(const TwF& t, float& r0, float& i0, float& r1, float& i1){
    {   // span 64: (r0-r1) * W^l, W=e^{-2pi i/128}
        float ar = r0 + r1, ai = i0 + i1;
        float br = r0 - r1, bi = i0 - i1;
        r0 = ar; i0 = ai;
        r1 =  br*t.c6 + bi*t.s6;
        i1 = -br*t.s6 + bi*t.c6;
    }
    #pragma unroll
    for (int lg = 5; lg >= 0; --lg){
        int m = 1 << lg;
        float cw = t.cw[lg], sw = t.sw[lg], sg = t.sg[lg];
        float pr = __shfl_xor(r0, m, 64), pi = __shfl_xor(i0, m, 64);
        float tr = fmaf(sg, r0, pr), ti = fmaf(sg, i0, pi);
        r0 = tr*cw - ti*sw;
        i0 = tr*sw + ti*cw;
        pr = __shfl_xor(r1, m, 64); pi = __shfl_xor(i1, m, 64);
        tr = fmaf(sg, r1, pr); ti = fmaf(sg, i1, pi);
        r1 = tr*cw - ti*sw;
        i1 = tr*sw + ti*cw;
    }
}

// DIT inverse (unnormalized): slot j holds X[rev7(j)] in, natural out. W = e^{+2pi i/128}
__device__ __forceinline__ void dit128t(const TwI& t, float& r0, float& i0, float& r1, float& i1){
    const int l = threadIdx.x & 63;
    #pragma unroll
    for (int lg = 0; lg <= 5; ++lg){
        int m = 1 << lg;
        bool up = (l & m) != 0;
        float cw = t.cw[lg], sw = t.sw[lg];
        float pr = __shfl_xor(r0, m, 64), pi = __shfl_xor(i0, m, 64);
        float vr = up ? r0 : pr, vi = up ? i0 : pi;
        float ar = up ? pr : r0, ai = up ? pi : i0;
        r0 = fmaf(vr, cw, fmaf(vi, -sw, ar));
        i0 = fmaf(vr, sw, fmaf(vi,  cw, ai));
        pr = __shfl_xor(r1, m, 64); pi = __shfl_xor(i1, m, 64);
        vr = up ? r1 : pr; vi = up ? i1 : pi;
        ar = up ? pr : r1; ai = up ? pi : i1;
        r1 = fmaf(vr, cw, fmaf(vi, -sw, ar));
        i1 = fmaf(vr, sw, fmaf(vi,  cw, ai));
    }
    {   // span 64: w = e^{+2pi i l/128}
        float wr = r1*t.c6 - i1*t.s6, wi = r1*t.s6 + i1*t.c6;
        float ar = r0 + wr, ai = i0 + wi;
        r1 = r0 - wr; i1 = i0 - wi;
        r0 = ar; i0 = ai;
    }
}

// ---------- K1: fused forward fft2 per image, 1024 threads ----------
// LDS transpose plane is fp16-packed (re|im in one u32): 66 KB -> 2 blocks/CU.
__global__ __launch_bounds__(1024, 8) void k_fft2_fwd(const float* __restrict__ x,
                                                   float* __restrict__ ore, float* __restrict__ oim,
                                                   float* __restrict__ norm2){
    __shared__ unsigned sp[128*129];
    __shared__ float red[16];
    int lane = threadIdx.x & 63, wave = threadIdx.x >> 6;
    int img = blockIdx.x;
    TwF tw; make_twf(tw);
    const float* base = x + (size_t)img * NFFT;
    #pragma unroll 2
    for (int it = 0; it < 8; ++it){
        int h = (wave << 3) + it;
        float a0 = base[h*128 + lane], b0 = 0.f;
        float a1 = base[h*128 + lane + 64], b1 = 0.f;
        dif128t(tw, a0, b0, a1, b1);
        sp[lane*129 + h]      = packh(a0, b0);
        sp[(lane+64)*129 + h] = packh(a1, b1);
    }
    __syncthreads();
    float acc = 0.f;
    #pragma unroll 2
    for (int it = 0; it < 8; ++it){
        int j = (wave << 3) + it;
        float a0, b0, a1, b1;
        unpackh(sp[j*129 + lane],      a0, b0);
        unpackh(sp[j*129 + lane + 64], a1, b1);
        dif128t(tw, a0, b0, a1, b1);
        size_t o = (size_t)img*NFFT + (size_t)j*128;
        ore[o + lane] = a0;      oim[o + lane] = b0;
        ore[o + lane + 64] = a1; oim[o + lane + 64] = b1;
        acc += a0*a0 + b0*b0 + a1*a1 + b1*b1;
    }
    #pragma unroll
    for (int m = 32; m >= 1; m >>= 1) acc += __shfl_xor(acc, m, 64);
    if (lane == 0) red[wave] = acc;
    __syncthreads();
    if (threadIdx.x == 0){
        float s = 0.f;
        #pragma unroll
        for (int i = 0; i < 16; ++i) s += red[i];
        norm2[img] = s;
    }
}

// ---------- K2: gram partials, atomic-free ----------
__global__ __launch_bounds__(256) void k_gram(const float* __restrict__ xre, const float* __restrict__ xim,
                                              float* __restrict__ Gpart){
    __shared__ float lr[64*36], li[64*36];
    int t = threadIdx.x, lane = t & 63, wave = t >> 6;
    int bh = blockIdx.x >> 5;
    int n0 = (blockIdx.x & 31) << 9;
    size_t cbase = (size_t)bh * 32 * NFFT;
    int c0 = (lane >> 3) << 2, d0 = (lane & 7) << 2;
    float are[16], aim[16];
    #pragma unroll
    for (int i = 0; i < 16; ++i){ are[i] = 0.f; aim[i] = 0.f; }
    for (int nt = 0; nt < 8; ++nt){
        int nb = n0 + (nt << 6);
        __syncthreads();
        #pragma unroll
        for (int r = 0; r < 8; ++r){
            int ch = (wave << 3) + r;
            lr[lane*36 + ch] = xre[cbase + (size_t)ch*NFFT + nb + lane];
            li[lane*36 + ch] = xim[cbase + (size_t)ch*NFFT + nb + lane];
        }
        __syncthreads();
        for (int j = (wave<<4); j < (wave<<4) + 16; ++j){
            float4 xr = *(const float4*)&lr[j*36 + c0];
            float4 xi = *(const float4*)&li[j*36 + c0];
            float4 yr = *(const float4*)&lr[j*36 + d0];
            float4 yi = *(const float4*)&li[j*36 + d0];
            const float xrv[4] = {xr.x, xr.y, xr.z, xr.w};
            const float xiv[4] = {xi.x, xi.y, xi.z, xi.w};
            const float yrv[4] = {yr.x, yr.y, yr.z, yr.w};
            const float yiv[4] = {yi.x, yi.y, yi.z, yi.w};
            #pragma unroll
            for (int ci = 0; ci < 4; ++ci)
                #pragma unroll
                for (int di = 0; di < 4; ++di){
                    are[ci*4+di] += xrv[ci]*yrv[di] - xiv[ci]*yiv[di];
                    aim[ci*4+di] += xrv[ci]*yiv[di] + xiv[ci]*yrv[di];
                }
        }
    }
    float* gp = Gpart + ((size_t)blockIdx.x * 4 + wave) * 2048;
    #pragma unroll
    for (int ci = 0; ci < 4; ++ci)
        #pragma unroll
        for (int di = 0; di < 4; ++di){
            int idx = ((c0+ci)*32 + d0+di) * 2;
            gp[idx]     = are[ci*4+di];
            gp[idx + 1] = aim[ci*4+di];
        }
}

// ---------- K2b: reduce 128 partials per bh ----------
__global__ __launch_bounds__(256) void k_gram_red(const float* __restrict__ Gpart, float* __restrict__ G){
    int bh = blockIdx.x >> 3;
    int q  = ((blockIdx.x & 7) << 8) + threadIdx.x;
    const float* gp = Gpart + (size_t)bh * 128 * 2048 + q;
    float s = 0.f;
    #pragma unroll 8
    for (int p = 0; p < 128; ++p) s += gp[(size_t)p * 2048];
    G[(size_t)bh * 2048 + q] = s;
}

// ---------- K3: normalize, temperature, complex softmax, fold IF32 * (1/524288) ----------
__global__ __launch_bounds__(256) void k_attn(const float* __restrict__ G, const float* __restrict__ norm2,
                                              const float* __restrict__ temp, float* __restrict__ attn2){
    __shared__ float ar[32*33], ai[32*33];
    int bh = blockIdx.x, h = bh & 7, t = threadIdx.x;
    if (t < 32){
        float tv = temp[h];
        float nc = fmaxf(sqrtf(norm2[(bh<<5) + t]), 1e-12f);
        const float* gr = G + (size_t)bh*2048 + t*64;
        float mr = -1e30f, mi = -1e30f;
        for (int d = 0; d < 32; ++d){
            float nd = fmaxf(sqrtf(norm2[(bh<<5) + d]), 1e-12f);
            float s = tv / (nc * nd);
            float vr = gr[d*2] * s, vi = gr[d*2+1] * s;
            ar[t*33+d] = vr; ai[t*33+d] = vi;
            mr = fmaxf(mr, vr); mi = fmaxf(mi, vi);
        }
        float sr = 0.f, si = 0.f;
        for (int d = 0; d < 32; ++d){
            float er = __expf(ar[t*33+d] - mr), ei = __expf(ai[t*33+d] - mi);
            ar[t*33+d] = er; ai[t*33+d] = ei; sr += er; si += ei;
        }
        sr = 1.f/sr; si = 1.f/si;
        for (int d = 0; d < 32; ++d){ ar[t*33+d] *= sr; ai[t*33+d] *= si; }
    }
    __syncthreads();
    const float S = 1.f / 524288.f;
    for (int q = t; q < 1024; q += 256){
        int e = q >> 5, d = q & 31;
        float sr = 0.f, si = 0.f;
        for (int c = 0; c < 32; ++c){
            float sn, cs; sincos_rev((float)((e*c) & 31) * 0.03125f, sn, cs);
            float xr = ar[c*33+d], xi = ai[c*33+d];
            sr += cs*xr - sn*xi;
            si += cs*xi + sn*xr;
        }
        attn2[(size_t)bh*2048 + q*2]     = sr * S;
        attn2[(size_t)bh*2048 + q*2 + 1] = si * S;
    }
}

// ---------- K4: mix[e][n] = sum_d attn2[e][d] * X[d][n]  (complex) ----------
__global__ __launch_bounds__(256) void k_mix(const float* __restrict__ xre, const float* __restrict__ xim,
                                             const float* __restrict__ attn2,
                                             float* __restrict__ ore, float* __restrict__ oim){
    __shared__ float a2[2048];
    __shared__ float lr[32*65], li[32*65];
    int t = threadIdx.x, lane = t & 63, wave = t >> 6;
    int bh = blockIdx.x >> 5;
    int n0 = (blockIdx.x & 31) << 9;
    size_t cbase = (size_t)bh * 32 * NFFT;
    {
        const float4* s4 = (const float4*)(attn2 + (size_t)bh*2048);
        float4* d4 = (float4*)a2;
        d4[t] = s4[t]; d4[t + 256] = s4[t + 256];
    }
    for (int tile = 0; tile < 8; ++tile){
        int nb = n0 + (tile << 6);
        __syncthreads();
        #pragma unroll
        for (int r = 0; r < 8; ++r){
            int ch = (wave << 3) + r;
            lr[ch*65 + lane] = xre[cbase + (size_t)ch*NFFT + nb + lane];
            li[ch*65 + lane] = xim[cbase + (size_t)ch*NFFT + nb + lane];
        }
        __syncthreads();
        float accr[8] = {0,0,0,0,0,0,0,0}, acci[8] = {0,0,0,0,0,0,0,0};
        for (int d = 0; d < 32; d += 2){
            float xr0 = lr[d*65 + lane],     xi0 = li[d*65 + lane];
            float xr1 = lr[(d+1)*65 + lane], xi1 = li[(d+1)*65 + lane];
            #pragma unroll
            for (int k = 0; k < 8; ++k){
                int e = (wave << 3) + k;
                const float4 w = *(const float4*)&a2[(e << 6) + (d << 1)];
                accr[k] += w.x*xr0 - w.y*xi0 + w.z*xr1 - w.w*xi1;
                acci[k] += w.x*xi0 + w.y*xr0 + w.z*xi1 + w.w*xr1;
            }
        }
        #pragma unroll
        for (int k = 0; k < 8; ++k){
            int e = (wave << 3) + k;
            ore[cbase + (size_t)e*NFFT + nb + lane] = accr[k];
            oim[cbase + (size_t)e*NFFT + nb + lane] = acci[k];
        }
    }
}

// ---------- K5: fused 16384-pt inverse FFT + abs per row, 1024 threads; PACKED bf16(hi|lo) into io ----------
// LDS transpose plane is fp16-packed: 66 KB -> 2 blocks/CU (was 132 KB -> 1 block/CU).
__global__ __launch_bounds__(1024, 8) void k_ifft_n(const float* ire, float* io){
    __shared__ unsigned sp[128*129];
    int lane = threadIdx.x & 63, wave = threadIdx.x >> 6;
    size_t rb = (size_t)blockIdx.x * NFFT;
    TwI tw; make_twi(tw);
    #pragma unroll 2
    for (int it = 0; it < 8; ++it){
        int jw = (wave << 3) + it;
        size_t base = rb + ((size_t)jw << 7);
        float a0 = ire[base + lane], b0 = io[base + lane];
        float a1 = ire[base + lane + 64], b1 = io[base + lane + 64];
        dit128t(tw, a0, b0, a1, b1);
        int kw = rev7(jw);
        float sn, cs;
        sincos_rev((float)(lane * kw) * 6.103515625e-05f, sn, cs);
        float r = a0*cs - b0*sn, i2 = a0*sn + b0*cs;
        sp[lane*129 + jw] = packh(r, i2);
        sincos_rev((float)((lane + 64) * kw) * 6.103515625e-05f, sn, cs);
        r = a1*cs - b1*sn; i2 = a1*sn + b1*cs;
        sp[(lane+64)*129 + jw] = packh(r, i2);
    }
    __syncthreads();
    unsigned av[8][2];
    #pragma unroll 2
    for (int it = 0; it < 8; ++it){
        int pw = (wave << 3) + it;
        float a0, b0, a1, b1;
        unpackh(sp[pw*129 + lane],      a0, b0);
        unpackh(sp[pw*129 + lane + 64], a1, b1);
        dit128t(tw, a0, b0, a1, b1);
        av[it][0] = packsplit(sqrtf(a0*a0 + b0*b0));
        av[it][1] = packsplit(sqrtf(a1*a1 + b1*b1));
    }
    __syncthreads();
    #pragma unroll 2
    for (int it = 0; it < 8; ++it){
        int pw = (wave << 3) + it;
        sp[lane*129 + pw] = av[it][0];
        sp[(lane+64)*129 + pw] = av[it][1];
    }
    __syncthreads();
    int row = threadIdx.x >> 3, cb = (threadIdx.x & 7) << 4;
    size_t ob = rb + ((size_t)row << 7) + cb;
    const unsigned* s = &sp[row*129 + cb];
    unsigned* od = (unsigned*)io;
    #pragma unroll
    for (int q = 0; q < 4; ++q)
        *(uint4*)(od + ob + (q << 2)) = make_uint4(s[q*4], s[q*4+1], s[q*4+2], s[q*4+3]);
}

// ---------- K6: gating, IN-PLACE, 4-way split for occupancy ----------
__global__ __launch_bounds__(256) void k_gate(float* xre, float* xim,
                                              const float* __restrict__ w1, const float* __restrict__ b1,
                                              const float* __restrict__ bg, const float* __restrict__ bb_,
                                              const float* __restrict__ bm, const float* __restrict__ bv,
                                              const float* __restrict__ w2, const float* __restrict__ b2){
    __shared__ float w1T[256*17];
    __shared__ float w2s[256*16];
    __shared__ float yred[256*17];
    int t = threadIdx.x, g = t >> 6, col = t & 63;
    #pragma unroll
    for (int i = 0; i < 16; ++i) w1T[t*17 + i] = w1[i*256 + t];
    {
        const float4* s4 = (const float4*)w2; float4* d4 = (float4*)w2s;
        #pragma unroll
        for (int i = 0; i < 4; ++i) d4[i*256 + t] = s4[i*256 + t];
    }
    __syncthreads();
    int b = blockIdx.x >> 8;
    int n = ((blockIdx.x & 255) << 6) + col;
    size_t base = ((size_t)b << 8) * NFFT + n;
    float y[16];
    #pragma unroll
    for (int r = 0; r < 16; ++r) y[r] = 0.f;
    for (int c = g << 6; c < (g << 6) + 64; ++c){
        float xr = xre[base + (size_t)c*NFFT];
        #pragma unroll
        for (int r = 0; r < 16; ++r) y[r] += w1T[c*17 + r] * xr;
    }
    #pragma unroll
    for (int r = 0; r < 16; ++r) yred[t*17 + r] = y[r];
    __syncthreads();
    #pragma unroll
    for (int r = 0; r < 16; ++r){
        float v = yred[col*17 + r] + yred[(col+64)*17 + r]
                + yred[(col+128)*17 + r] + yred[(col+192)*17 + r] + b1[r];
        v = (v - bm[r]) * rsqrtf(bv[r] + 1e-5f) * bg[r] + bb_[r];
        y[r] = fmaxf(v, 0.f);
    }
    for (int o = g << 6; o < (g << 6) + 64; ++o){
        float s = b2[o];
        #pragma unroll
        for (int r = 0; r < 16; ++r) s += w2s[o*16 + r] * y[r];
        float gg = 1.f / (1.f + __expf(-s)) * 6.103515625e-05f;   // sigmoid * 1/16384
        float xr = xre[base + (size_t)o*NFFT];
        float xi = xim[base + (size_t)o*NFFT];
        xre[base + (size_t)o*NFFT] = gg * xr;
        xim[base + (size_t)o*NFFT] = gg * xi;
    }
}

// ---------- K7: fused ifft2 per image + abs, 1024 threads -> PACKED bf16(hi|lo) into re plane ----------
// LDS transpose plane is fp16-packed: 66 KB -> 2 blocks/CU.
__global__ __launch_bounds__(1024, 8) void k_ifft2_gate(float* re_io, const float* im_){
    __shared__ unsigned sp[128*129];
    int lane = threadIdx.x & 63, wave = threadIdx.x >> 6;
    size_t ib = (size_t)blockIdx.x * NFFT;
    TwI tw; make_twi(tw);
    #pragma unroll 2
    for (int it = 0; it < 8; ++it){
        int jw = (wave << 3) + it;
        size_t base = ib + ((size_t)jw << 7);
        float a0 = re_io[base + lane], b0 = im_[base + lane];
        float a1 = re_io[base + lane + 64], b1 = im_[base + lane + 64];
        dit128t(tw, a0, b0, a1, b1);
        sp[lane*129 + jw]      = packh(a0, b0);
        sp[(lane+64)*129 + jw] = packh(a1, b1);
    }
    __syncthreads();
    #pragma unroll 2
    for (int it = 0; it < 8; ++it){
        int ph = (wave << 3) + it;
        float a0, b0, a1, b1;
        unpackh(sp[ph*129 + lane],      a0, b0);
        unpackh(sp[ph*129 + lane + 64], a1, b1);
        dit128t(tw, a0, b0, a1, b1);
        size_t o = ib + ((size_t)ph << 7);
        re_io[o + lane]      = __uint_as_float(packsplit(sqrtf(a0*a0 + b0*b0)));
        re_io[o + lane + 64] = __uint_as_float(packsplit(sqrtf(a1*a1 + b1*b1)));
    }
}

// ---------- K7b: pack pw into (hi|lo) u32 ----------
__global__ __launch_bounds__(256) void k_pw_cvt(const float* __restrict__ pw, unsigned* __restrict__ pwp){
    int i = (blockIdx.x << 10) + (threadIdx.x << 2);
    float4 v = *(const float4*)(pw + i);
    uint4 o;
    o.x = packsplit(v.x); o.y = packsplit(v.y); o.z = packsplit(v.z); o.w = packsplit(v.w);
    *(uint4*)(pwp + i) = o;
}

// ---------- K8: projection via bf16 MFMA, pre-packed inputs ----------
union FU { bf16x8 v; unsigned u[4]; };

__global__ __launch_bounds__(256) void k_proj(const unsigned* __restrict__ cat0, const unsigned* __restrict__ cat1,
                                              const unsigned* __restrict__ pwp, float* __restrict__ out){
    __shared__ unsigned As[128*33];   // [o][k] packed, stride 33
    __shared__ unsigned Bs[32*129];   // [k][n] packed, stride 129
    int t = threadIdx.x, lane = t & 63, wave = t >> 6;
    int quad = lane >> 4, l15 = lane & 15;
    int b  = blockIdx.x >> 8;
    int mo = (blockIdx.x >> 7) & 1;
    int nt = blockIdx.x & 127;
    int n0 = nt << 7;
    int wr = (wave >> 1) << 6;
    int wc = (wave & 1) << 6;

    f32x4 acc[4][4];
    #pragma unroll
    for (int i = 0; i < 4; ++i)
        #pragma unroll
        for (int j = 0; j < 4; ++j) acc[i][j] = (f32x4){0.f,0.f,0.f,0.f};

    int ao = t >> 1, ak = (t & 1) << 4;
    int bk = t >> 5, bn = t & 31;

    for (int ks = 0; ks < 16; ++ks){
        int k0 = ks << 5;
        __syncthreads();
        {
            const unsigned* ap = pwp + (size_t)((mo << 7) + ao)*512 + k0 + ak;
            #pragma unroll
            for (int i = 0; i < 16; ++i) As[ao*33 + ak + i] = ap[i];
        }
        {
            #pragma unroll
            for (int p = 0; p < 4; ++p){
                int q = k0 + (p << 3) + bk;
                const unsigned* srow = (q < 256) ? (cat0 + (size_t)((b<<8) + q) * NFFT)
                                                 : (cat1 + (size_t)((b<<8) + (q-256)) * NFFT);
                #pragma unroll
                for (int i = 0; i < 4; ++i){
                    int n = bn + (i << 5);
                    Bs[((p<<3) + bk)*129 + n] = srow[n0 + n];
                }
            }
        }
        __syncthreads();
        FU Ah[4], Al[4], Bh[4], Bl[4];
        #pragma unroll
        for (int mi = 0; mi < 4; ++mi){
            const unsigned* ap = &As[(wr + (mi << 4) + l15)*33 + (quad << 3)];
            #pragma unroll
            for (int p = 0; p < 4; ++p){
                unsigned e0 = ap[2*p], e1 = ap[2*p+1];
                Ah[mi].u[p] = (e0 >> 16) | (e1 & 0xFFFF0000u);
                Al[mi].u[p] = (e0 & 0xFFFFu) | (e1 << 16);
            }
        }
        #pragma unroll
        for (int ni = 0; ni < 4; ++ni){
            int n = wc + (ni << 4) + l15;
            #pragma unroll
            for (int p = 0; p < 4; ++p){
                unsigned e0 = Bs[((quad << 3) + 2*p)*129 + n];
                unsigned e1 = Bs[((quad << 3) + 2*p + 1)*129 + n];
                Bh[ni].u[p] = (e0 >> 16) | (e1 & 0xFFFF0000u);
                Bl[ni].u[p] = (e0 & 0xFFFFu) | (e1 << 16);
            }
        }
        #pragma unroll
        for (int mi = 0; mi < 4; ++mi)
            #pragma unroll
            for (int ni = 0; ni < 4; ++ni){
                acc[mi][ni] = __builtin_amdgcn_mfma_f32_16x16x32_bf16(Ah[mi].v, Bh[ni].v, acc[mi][ni], 0, 0, 0);
                acc[mi][ni] = __builtin_amdgcn_mfma_f32_16x16x32_bf16(Ah[mi].v, Bl[ni].v, acc[mi][ni], 0, 0, 0);
                acc[mi][ni] = __builtin_amdgcn_mfma_f32_16x16x32_bf16(Al[mi].v, Bh[ni].v, acc[mi][ni], 0, 0, 0);
            }
    }
    size_t obase = (size_t)((b << 8) + (mo << 7));
    #pragma unroll
    for (int mi = 0; mi < 4; ++mi)
        #pragma unroll
        for (int ni = 0; ni < 4; ++ni){
            int o_ = wr + (mi << 4) + (quad << 2);
            int n_ = n0 + wc + (ni << 4) + l15;
            float* op = out + (obase + o_)*NFFT + n_;
            #pragma unroll
            for (int r = 0; r < 4; ++r) op[(size_t)r*NFFT] = acc[mi][ni][r];
        }
}

// ---------- host ----------
extern "C" void kernel_launch(void* const* d_in, const int* in_sizes, int n_in,
                              void* d_out, int out_size, void* d_ws, size_t ws_size,
                              hipStream_t stream) {
    const float* x    = (const float*)d_in[0];
    const float* temp = (const float*)d_in[1];
    const float* w1   = (const float*)d_in[2];
    const float* b1   = (const float*)d_in[3];
    const float* bg   = (const float*)d_in[4];
    const float* bb_  = (const float*)d_in[5];
    const float* bm   = (const float*)d_in[6];
    const float* bv   = (const float*)d_in[7];
    const float* w2   = (const float*)d_in[8];
    const float* b2   = (const float*)d_in[9];
    const float* pw   = (const float*)d_in[10];
    float* out = (float*)d_out;

    float* ws = (float*)d_ws;
    float* Are  = ws;            // spectrum re -> gated in-place -> cat1 (packed)
    float* Aim  = ws + NP;       // spectrum im
    float* Ecat = ws + 2*NP;     // Gpart scratch -> mix im -> cat0 (packed, in-place)
    float* norm2 = ws + 3*NP;                  // 1024
    float* G     = norm2 + 1024;               // 65536
    float* attn2 = G + 65536;                  // 65536
    unsigned* pwpack = (unsigned*)(attn2 + 65536);  // 131072
    float* mixre = out;                        // d_out doubles as mix-re scratch
    float* Gpart = Ecat;                       // 8.4M floats, dead until k_mix

    size_t need = (3*NP + 1024 + 65536 + 65536 + 131072) * sizeof(float);
    if (ws_size < need) return;

    k_pw_cvt<<<128, 256, 0, stream>>>(pw, pwpack);
    k_fft2_fwd<<<1024, 1024, 0, stream>>>(x, Are, Aim, norm2);
    k_gram<<<1024, 256, 0, stream>>>(Are, Aim, Gpart);
    k_gram_red<<<256, 256, 0, stream>>>(Gpart, G);
    k_attn<<<32, 256, 0, stream>>>(G, norm2, temp, attn2);
    k_mix<<<1024, 256, 0, stream>>>(Are, Aim, attn2, mixre, Ecat);
    k_ifft_n<<<1024, 1024, 0, stream>>>(mixre, Ecat);
    k_gate<<<1024, 256, 0, stream>>>(Are, Aim, w1, b1, bg, bb_, bm, bv, w2, b2);
    k_ifft2_gate<<<1024, 1024, 0, stream>>>(Are, Aim);
    k_proj<<<1024, 256, 0, stream>>>((const unsigned*)Ecat, (const unsigned*)Are, pwpack, out);
    (void)in_sizes; (void)n_in; (void)out_size; (void)ws_size;
}

// Round 3
// 633.359 us; speedup vs baseline: 1.1704x; 1.1328x over previous
//
#include <hip/hip_runtime.h>
#include <math.h>

// Problem constants: b=4, c=256, heads=8, c/head=32, h=w=128, n=16384, cr=16
#define NFFT 16384
static constexpr size_t NP = 16777216; // one plane = 1024 * 16384 floats

typedef short bf16x8 __attribute__((ext_vector_type(8)));
typedef float f32x4  __attribute__((ext_vector_type(4)));
typedef __fp16 h16x2 __attribute__((ext_vector_type(2)));

union FU { bf16x8 v; unsigned u[4]; };

// ---------- helpers ----------
__device__ __forceinline__ void sincos_rev(float rv, float& sn, float& cs){
    sn = __builtin_amdgcn_sinf(rv);   // sin(2*pi*rv)
    cs = __builtin_amdgcn_cosf(rv);
}
__device__ __forceinline__ int rev7(int v){ return (int)(__brev((unsigned)v) >> 25); }

__device__ __forceinline__ unsigned f2bf(float f){
    unsigned u = __float_as_uint(f);
    return (u + 0x7FFFu + ((u >> 16) & 1u)) >> 16;   // round-to-nearest-even
}
__device__ __forceinline__ float bf2f(unsigned h){ return __uint_as_float(h << 16); }
// pack fp32 -> (bf16 hi | bf16 lo) in one u32, stored via float bit-pattern
__device__ __forceinline__ unsigned packsplit(float v){
    unsigned h = f2bf(v);
    float r = v - bf2f(h);
    unsigned l = f2bf(r);
    return (h << 16) | l;
}

// fp16x2 pack/unpack for the LDS transpose plane (single u32 per complex value).
union HU2 { h16x2 h; unsigned u; };
__device__ __forceinline__ unsigned packh(float a, float b){
    HU2 z; z.h = __builtin_amdgcn_cvt_pkrtz(a, b); return z.u;
}
__device__ __forceinline__ void unpackh(unsigned u, float& a, float& b){
    HU2 z; z.u = u; a = (float)z.h.x; b = (float)z.h.y;
}

// ---------- sign/identity-folded per-lane twiddles ----------
struct TwF { float cw[6], sw[6], sg[6], c6, s6; };
__device__ __forceinline__ void make_twf(TwF& t){
    const int l = threadIdx.x & 63;
    #pragma unroll
    for (int lg = 0; lg < 6; ++lg){
        int m = 1 << lg;
        bool up = (l & m) != 0;
        int e = (l & (m-1)) * (64 >> lg);
        float sn, cs; sincos_rev((float)e * 0.0078125f, sn, cs);
        t.cw[lg] = up ? cs : 1.f;
        t.sw[lg] = up ? -sn : 0.f;
        t.sg[lg] = up ? -1.f : 1.f;
    }
    sincos_rev((float)l * 0.0078125f, t.s6, t.c6);
}
struct TwI { float cw[6], sw[6], c6, s6; };
__device__ __forceinline__ void make_twi(TwI& t){
    const int l = threadIdx.x & 63;
    #pragma unroll
    for (int lg = 0; lg < 6; ++lg){
        int m = 1 << lg;
        bool up = (l & m) != 0;
        int e = (l & (m-1)) * (64 >> lg);
        float sn, cs; sincos_rev((float)e * 0.0078125f, sn, cs);
        t.cw[lg] = up ? -cs : cs;
        t.sw[lg] = up ? -sn : sn;
    }
    sincos_rev((float)l * 0.0078125f, t.s6, t.c6);
}

// DIF forward: natural in, slot j holds X[rev7(j)] out. W = e^{-2pi i/128}
__device__ __forceinline__ void dif128t(const TwF& t, float& r0, float& i0, float& r1, float& i1){
    {
        float ar = r0 + r1, ai = i0 + i1;
        float br = r0 - r1, bi = i0 - i1;
        r0 = ar; i0 = ai;
        r1 =  br*t.c6 + bi*t.s6;
        i1 = -br*t.s6 + bi*t.c6;
    }
    #pragma unroll
    for (int lg = 5; lg >= 0; --lg){
        int m = 1 << lg;
        float cw = t.cw[lg], sw = t.sw[lg], sg = t.sg[lg];
        float pr = __shfl_xor(r0, m, 64), pi = __shfl_xor(i0, m, 64);
        float tr = fmaf(sg, r0, pr), ti = fmaf(sg, i0, pi);
        r0 = tr*cw - ti*sw;
        i0 = tr*sw + ti*cw;
        pr = __shfl_xor(r1, m, 64); pi = __shfl_xor(i1, m, 64);
        tr = fmaf(sg, r1, pr); ti = fmaf(sg, i1, pi);
        r1 = tr*cw - ti*sw;
        i1 = tr*sw + ti*cw;
    }
}

// DIT inverse (unnormalized): slot j holds X[rev7(j)] in, natural out. W = e^{+2pi i/128}
__device__ __forceinline__ void dit128t(const TwI& t, float& r0, float& i0, float& r1, float& i1){
    const int l = threadIdx.x & 63;
    #pragma unroll
    for (int lg = 0; lg <= 5; ++lg){
        int m = 1 << lg;
        bool up = (l & m) != 0;
        float cw = t.cw[lg], sw = t.sw[lg];
        float pr = __shfl_xor(r0, m, 64), pi = __shfl_xor(i0, m, 64);
        float vr = up ? r0 : pr, vi = up ? i0 : pi;
        float ar = up ? pr : r0, ai = up ? pi : i0;
        r0 = fmaf(vr, cw, fmaf(vi, -sw, ar));
        i0 = fmaf(vr, sw, fmaf(vi,  cw, ai));
        pr = __shfl_xor(r1, m, 64); pi = __shfl_xor(i1, m, 64);
        vr = up ? r1 : pr; vi = up ? i1 : pi;
        ar = up ? pr : r1; ai = up ? pi : i1;
        r1 = fmaf(vr, cw, fmaf(vi, -sw, ar));
        i1 = fmaf(vr, sw, fmaf(vi,  cw, ai));
    }
    {
        float wr = r1*t.c6 - i1*t.s6, wi = r1*t.s6 + i1*t.c6;
        float ar = r0 + wr, ai = i0 + wi;
        r1 = r0 - wr; i1 = i0 - wi;
        r0 = ar; i0 = ai;
    }
}

// ---------- K1: fused forward fft2 per image, 1024 threads ----------
__global__ __launch_bounds__(1024, 8) void k_fft2_fwd(const float* __restrict__ x,
                                                   float* __restrict__ ore, float* __restrict__ oim,
                                                   float* __restrict__ norm2){
    __shared__ unsigned sp[128*129];
    __shared__ float red[16];
    int lane = threadIdx.x & 63, wave = threadIdx.x >> 6;
    int img = blockIdx.x;
    TwF tw; make_twf(tw);
    const float* base = x + (size_t)img * NFFT;
    #pragma unroll 2
    for (int it = 0; it < 8; ++it){
        int h = (wave << 3) + it;
        float a0 = base[h*128 + lane], b0 = 0.f;
        float a1 = base[h*128 + lane + 64], b1 = 0.f;
        dif128t(tw, a0, b0, a1, b1);
        sp[lane*129 + h]      = packh(a0, b0);
        sp[(lane+64)*129 + h] = packh(a1, b1);
    }
    __syncthreads();
    float acc = 0.f;
    #pragma unroll 2
    for (int it = 0; it < 8; ++it){
        int j = (wave << 3) + it;
        float a0, b0, a1, b1;
        unpackh(sp[j*129 + lane],      a0, b0);
        unpackh(sp[j*129 + lane + 64], a1, b1);
        dif128t(tw, a0, b0, a1, b1);
        size_t o = (size_t)img*NFFT + (size_t)j*128;
        ore[o + lane] = a0;      oim[o + lane] = b0;
        ore[o + lane + 64] = a1; oim[o + lane + 64] = b1;
        acc += a0*a0 + b0*b0 + a1*a1 + b1*b1;
    }
    #pragma unroll
    for (int m = 32; m >= 1; m >>= 1) acc += __shfl_xor(acc, m, 64);
    if (lane == 0) red[wave] = acc;
    __syncthreads();
    if (threadIdx.x == 0){
        float s = 0.f;
        #pragma unroll
        for (int i = 0; i < 16; ++i) s += red[i];
        norm2[img] = s;
    }
}

// ---------- K2: gram via bf16 MFMA ----------
// G[bh][c][d] = sum_n X[c][n]*X[d][n] (complex, no conj).
// A-frag and B-frag of mfma_16x16x32_bf16 have identical lane maps (row/col=lane&15,
// k=(lane>>4)*8+i), and gram's B == A, so one b128 LDS read serves both operands.
// Gre = Xr*Xr^T + (-Xi)*Xi^T (sign via bf16 XOR); Gim = Xr*Xi^T + Xi*Xr^T.
// Grid: 32 bh x 32 ksplit = 1024 blocks, K=512 each, 2 staged tiles of 256.
__global__ __launch_bounds__(256) void k_gram(const float* __restrict__ xre, const float* __restrict__ xim,
                                              float* __restrict__ Gpart){
    __shared__ unsigned lds[2*32*132];   // 2 planes x 32 ch x 132 u32 (2 bf16/u32), 33792 B
    int t = threadIdx.x, lane = t & 63, wave = t >> 6;
    int bh = blockIdx.x >> 5;          // 32
    int ks = blockIdx.x & 31;          // 32 k-splits, K=512 each
    size_t cbase = (size_t)bh * 32 * NFFT;
    int k0blk = ks << 9;

    int sc  = t >> 3;        // staging channel 0..31
    int sk4 = (t & 7) << 2;  // within-32-float chunk offset (8 lanes cover 32 consecutive k)

    f32x4 aRe[2][2], aIm[2][2];
    #pragma unroll
    for (int i = 0; i < 2; ++i)
        #pragma unroll
        for (int j = 0; j < 2; ++j){ aRe[i][j] = (f32x4){0,0,0,0}; aIm[i][j] = (f32x4){0,0,0,0}; }

    for (int tile = 0; tile < 2; ++tile){
        int kb = k0blk + (tile << 8);   // global k base of 256-wide tile
        __syncthreads();
        {   // stage fp32 -> packed bf16 pairs; thread's float4 #i at k = kb + i*32 + sk4
            const float* pr  = xre + cbase + (size_t)sc*NFFT + kb + sk4;
            const float* pi_ = xim + cbase + (size_t)sc*NFFT + kb + sk4;
            unsigned* dr = &lds[ sc*132 + (sk4 >> 1) ];
            unsigned* di = &lds[ 32*132 + sc*132 + (sk4 >> 1) ];
            #pragma unroll
            for (int i = 0; i < 8; ++i){
                float4 v = *(const float4*)(pr + (i << 5));
                dr[(i<<4)]     = f2bf(v.x) | (f2bf(v.y) << 16);
                dr[(i<<4) + 1] = f2bf(v.z) | (f2bf(v.w) << 16);
                v = *(const float4*)(pi_ + (i << 5));
                di[(i<<4)]     = f2bf(v.x) | (f2bf(v.y) << 16);
                di[(i<<4) + 1] = f2bf(v.z) | (f2bf(v.w) << 16);
            }
        }
        __syncthreads();
        #pragma unroll
        for (int ss = 0; ss < 2; ++ss){
            int s = wave + (ss << 2);                     // K-step 0..7 within tile
            int kbase = (s << 4) + ((lane >> 4) << 2);    // u32 index within ch row
            FU fr0, fr1, fi0, fi1, fn0, fn1;
            *(uint4*)fr0.u = *(const uint4*)&lds[ (lane & 15)*132 + kbase ];
            *(uint4*)fr1.u = *(const uint4*)&lds[ ((lane & 15) + 16)*132 + kbase ];
            *(uint4*)fi0.u = *(const uint4*)&lds[ 32*132 + (lane & 15)*132 + kbase ];
            *(uint4*)fi1.u = *(const uint4*)&lds[ 32*132 + ((lane & 15) + 16)*132 + kbase ];
            #pragma unroll
            for (int p = 0; p < 4; ++p){ fn0.u[p] = fi0.u[p] ^ 0x80008000u; fn1.u[p] = fi1.u[p] ^ 0x80008000u; }
            aRe[0][0] = __builtin_amdgcn_mfma_f32_16x16x32_bf16(fr0.v, fr0.v, aRe[0][0], 0, 0, 0);
            aRe[0][0] = __builtin_amdgcn_mfma_f32_16x16x32_bf16(fn0.v, fi0.v, aRe[0][0], 0, 0, 0);
            aRe[0][1] = __builtin_amdgcn_mfma_f32_16x16x32_bf16(fr0.v, fr1.v, aRe[0][1], 0, 0, 0);
            aRe[0][1] = __builtin_amdgcn_mfma_f32_16x16x32_bf16(fn0.v, fi1.v, aRe[0][1], 0, 0, 0);
            aRe[1][0] = __builtin_amdgcn_mfma_f32_16x16x32_bf16(fr1.v, fr0.v, aRe[1][0], 0, 0, 0);
            aRe[1][0] = __builtin_amdgcn_mfma_f32_16x16x32_bf16(fn1.v, fi0.v, aRe[1][0], 0, 0, 0);
            aRe[1][1] = __builtin_amdgcn_mfma_f32_16x16x32_bf16(fr1.v, fr1.v, aRe[1][1], 0, 0, 0);
            aRe[1][1] = __builtin_amdgcn_mfma_f32_16x16x32_bf16(fn1.v, fi1.v, aRe[1][1], 0, 0, 0);
            aIm[0][0] = __builtin_amdgcn_mfma_f32_16x16x32_bf16(fr0.v, fi0.v, aIm[0][0], 0, 0, 0);
            aIm[0][0] = __builtin_amdgcn_mfma_f32_16x16x32_bf16(fi0.v, fr0.v, aIm[0][0], 0, 0, 0);
            aIm[0][1] = __builtin_amdgcn_mfma_f32_16x16x32_bf16(fr0.v, fi1.v, aIm[0][1], 0, 0, 0);
            aIm[0][1] = __builtin_amdgcn_mfma_f32_16x16x32_bf16(fi0.v, fr1.v, aIm[0][1], 0, 0, 0);
            aIm[1][0] = __builtin_amdgcn_mfma_f32_16x16x32_bf16(fr1.v, fi0.v, aIm[1][0], 0, 0, 0);
            aIm[1][0] = __builtin_amdgcn_mfma_f32_16x16x32_bf16(fi1.v, fr0.v, aIm[1][0], 0, 0, 0);
            aIm[1][1] = __builtin_amdgcn_mfma_f32_16x16x32_bf16(fr1.v, fi1.v, aIm[1][1], 0, 0, 0);
            aIm[1][1] = __builtin_amdgcn_mfma_f32_16x16x32_bf16(fi1.v, fr1.v, aIm[1][1], 0, 0, 0);
        }
    }
    // cross-wave reduce: each lane's acc element -> (c,d); C/D map: c=(lane>>4)*4+r, d=lane&15
    __syncthreads();
    float* rbuf = (float*)lds;   // 4 waves x 2048 floats = 32 KB, fits
    int dcol = lane & 15, rrow = lane >> 4;
    #pragma unroll
    for (int i = 0; i < 2; ++i)
        #pragma unroll
        for (int j = 0; j < 2; ++j)
            #pragma unroll
            for (int r = 0; r < 4; ++r){
                int c = (i << 4) + (rrow << 2) + r;
                int d = (j << 4) + dcol;
                rbuf[wave*2048 + ((c << 5) + d)*2    ] = aRe[i][j][r];
                rbuf[wave*2048 + ((c << 5) + d)*2 + 1] = aIm[i][j][r];
            }
    __syncthreads();
    float* gp = Gpart + (size_t)blockIdx.x * 2048;
    for (int idx = t; idx < 2048; idx += 256)
        gp[idx] = rbuf[idx] + rbuf[2048 + idx] + rbuf[4096 + idx] + rbuf[6144 + idx];
}

// ---------- K2b: reduce 32 k-split partials per bh ----------
__global__ __launch_bounds__(256) void k_gram_red(const float* __restrict__ Gpart, float* __restrict__ G){
    int bh = blockIdx.x >> 3;
    int q  = ((blockIdx.x & 7) << 8) + threadIdx.x;
    const float* gp = Gpart + (size_t)bh * 32 * 2048 + q;
    float s = 0.f;
    #pragma unroll 8
    for (int p = 0; p < 32; ++p) s += gp[(size_t)p * 2048];
    G[(size_t)bh * 2048 + q] = s;
}

// ---------- K3: normalize, temperature, complex softmax, fold IF32 * (1/524288) ----------
__global__ __launch_bounds__(256) void k_attn(const float* __restrict__ G, const float* __restrict__ norm2,
                                              const float* __restrict__ temp, float* __restrict__ attn2){
    __shared__ float ar[32*33], ai[32*33];
    int bh = blockIdx.x, h = bh & 7, t = threadIdx.x;
    if (t < 32){
        float tv = temp[h];
        float nc = fmaxf(sqrtf(norm2[(bh<<5) + t]), 1e-12f);
        const float* gr = G + (size_t)bh*2048 + t*64;
        float mr = -1e30f, mi = -1e30f;
        for (int d = 0; d < 32; ++d){
            float nd = fmaxf(sqrtf(norm2[(bh<<5) + d]), 1e-12f);
            float s = tv / (nc * nd);
            float vr = gr[d*2] * s, vi = gr[d*2+1] * s;
            ar[t*33+d] = vr; ai[t*33+d] = vi;
            mr = fmaxf(mr, vr); mi = fmaxf(mi, vi);
        }
        float sr = 0.f, si = 0.f;
        for (int d = 0; d < 32; ++d){
            float er = __expf(ar[t*33+d] - mr), ei = __expf(ai[t*33+d] - mi);
            ar[t*33+d] = er; ai[t*33+d] = ei; sr += er; si += ei;
        }
        sr = 1.f/sr; si = 1.f/si;
        for (int d = 0; d < 32; ++d){ ar[t*33+d] *= sr; ai[t*33+d] *= si; }
    }
    __syncthreads();
    const float S = 1.f / 524288.f;
    for (int q = t; q < 1024; q += 256){
        int e = q >> 5, d = q & 31;
        float sr = 0.f, si = 0.f;
        for (int c = 0; c < 32; ++c){
            float sn, cs; sincos_rev((float)((e*c) & 31) * 0.03125f, sn, cs);
            float xr = ar[c*33+d], xi = ai[c*33+d];
            sr += cs*xr - sn*xi;
            si += cs*xi + sn*xr;
        }
        attn2[(size_t)bh*2048 + q*2]     = sr * S;
        attn2[(size_t)bh*2048 + q*2 + 1] = si * S;
    }
}

// ---------- K4: mix[e][n] = sum_d attn2[e][d] * X[d][n]  (complex) ----------
__global__ __launch_bounds__(256) void k_mix(const float* __restrict__ xre, const float* __restrict__ xim,
                                             const float* __restrict__ attn2,
                                             float* __restrict__ ore, float* __restrict__ oim){
    __shared__ float a2[2048];
    __shared__ float lr[32*65], li[32*65];
    int t = threadIdx.x, lane = t & 63, wave = t >> 6;
    int bh = blockIdx.x >> 5;
    int n0 = (blockIdx.x & 31) << 9;
    size_t cbase = (size_t)bh * 32 * NFFT;
    {
        const float4* s4 = (const float4*)(attn2 + (size_t)bh*2048);
        float4* d4 = (float4*)a2;
        d4[t] = s4[t]; d4[t + 256] = s4[t + 256];
    }
    for (int tile = 0; tile < 8; ++tile){
        int nb = n0 + (tile << 6);
        __syncthreads();
        #pragma unroll
        for (int r = 0; r < 8; ++r){
            int ch = (wave << 3) + r;
            lr[ch*65 + lane] = xre[cbase + (size_t)ch*NFFT + nb + lane];
            li[ch*65 + lane] = xim[cbase + (size_t)ch*NFFT + nb + lane];
        }
        __syncthreads();
        float accr[8] = {0,0,0,0,0,0,0,0}, acci[8] = {0,0,0,0,0,0,0,0};
        for (int d = 0; d < 32; d += 2){
            float xr0 = lr[d*65 + lane],     xi0 = li[d*65 + lane];
            float xr1 = lr[(d+1)*65 + lane], xi1 = li[(d+1)*65 + lane];
            #pragma unroll
            for (int k = 0; k < 8; ++k){
                int e = (wave << 3) + k;
                const float4 w = *(const float4*)&a2[(e << 6) + (d << 1)];
                accr[k] += w.x*xr0 - w.y*xi0 + w.z*xr1 - w.w*xi1;
                acci[k] += w.x*xi0 + w.y*xr0 + w.z*xi1 + w.w*xr1;
            }
        }
        #pragma unroll
        for (int k = 0; k < 8; ++k){
            int e = (wave << 3) + k;
            ore[cbase + (size_t)e*NFFT + nb + lane] = accr[k];
            oim[cbase + (size_t)e*NFFT + nb + lane] = acci[k];
        }
    }
}

// ---------- K5: fused 16384-pt inverse FFT + abs per row; PACKED bf16(hi|lo) into io ----------
__global__ __launch_bounds__(1024, 8) void k_ifft_n(const float* ire, float* io){
    __shared__ unsigned sp[128*129];
    int lane = threadIdx.x & 63, wave = threadIdx.x >> 6;
    size_t rb = (size_t)blockIdx.x * NFFT;
    TwI tw; make_twi(tw);
    #pragma unroll 2
    for (int it = 0; it < 8; ++it){
        int jw = (wave << 3) + it;
        size_t base = rb + ((size_t)jw << 7);
        float a0 = ire[base + lane], b0 = io[base + lane];
        float a1 = ire[base + lane + 64], b1 = io[base + lane + 64];
        dit128t(tw, a0, b0, a1, b1);
        int kw = rev7(jw);
        float sn, cs;
        sincos_rev((float)(lane * kw) * 6.103515625e-05f, sn, cs);
        float r = a0*cs - b0*sn, i2 = a0*sn + b0*cs;
        sp[lane*129 + jw] = packh(r, i2);
        sincos_rev((float)((lane + 64) * kw) * 6.103515625e-05f, sn, cs);
        r = a1*cs - b1*sn; i2 = a1*sn + b1*cs;
        sp[(lane+64)*129 + jw] = packh(r, i2);
    }
    __syncthreads();
    unsigned av[8][2];
    #pragma unroll 2
    for (int it = 0; it < 8; ++it){
        int pw = (wave << 3) + it;
        float a0, b0, a1, b1;
        unpackh(sp[pw*129 + lane],      a0, b0);
        unpackh(sp[pw*129 + lane + 64], a1, b1);
        dit128t(tw, a0, b0, a1, b1);
        av[it][0] = packsplit(sqrtf(a0*a0 + b0*b0));
        av[it][1] = packsplit(sqrtf(a1*a1 + b1*b1));
    }
    __syncthreads();
    #pragma unroll 2
    for (int it = 0; it < 8; ++it){
        int pw = (wave << 3) + it;
        sp[lane*129 + pw] = av[it][0];
        sp[(lane+64)*129 + pw] = av[it][1];
    }
    __syncthreads();
    int row = threadIdx.x >> 3, cb = (threadIdx.x & 7) << 4;
    size_t ob = rb + ((size_t)row << 7) + cb;
    const unsigned* s = &sp[row*129 + cb];
    unsigned* od = (unsigned*)io;
    #pragma unroll
    for (int q = 0; q < 4; ++q)
        *(uint4*)(od + ob + (q << 2)) = make_uint4(s[q*4], s[q*4+1], s[q*4+2], s[q*4+3]);
}

// ---------- K6: gating, IN-PLACE, 4-way split for occupancy ----------
__global__ __launch_bounds__(256) void k_gate(float* xre, float* xim,
                                              const float* __restrict__ w1, const float* __restrict__ b1,
                                              const float* __restrict__ bg, const float* __restrict__ bb_,
                                              const float* __restrict__ bm, const float* __restrict__ bv,
                                              const float* __restrict__ w2, const float* __restrict__ b2){
    __shared__ float w1T[256*17];
    __shared__ float w2s[256*16];
    __shared__ float yred[256*17];
    int t = threadIdx.x, g = t >> 6, col = t & 63;
    #pragma unroll
    for (int i = 0; i < 16; ++i) w1T[t*17 + i] = w1[i*256 + t];
    {
        const float4* s4 = (const float4*)w2; float4* d4 = (float4*)w2s;
        #pragma unroll
        for (int i = 0; i < 4; ++i) d4[i*256 + t] = s4[i*256 + t];
    }
    __syncthreads();
    int b = blockIdx.x >> 8;
    int n = ((blockIdx.x & 255) << 6) + col;
    size_t base = ((size_t)b << 8) * NFFT + n;
    float y[16];
    #pragma unroll
    for (int r = 0; r < 16; ++r) y[r] = 0.f;
    for (int c = g << 6; c < (g << 6) + 64; ++c){
        float xr = xre[base + (size_t)c*NFFT];
        #pragma unroll
        for (int r = 0; r < 16; ++r) y[r] += w1T[c*17 + r] * xr;
    }
    #pragma unroll
    for (int r = 0; r < 16; ++r) yred[t*17 + r] = y[r];
    __syncthreads();
    #pragma unroll
    for (int r = 0; r < 16; ++r){
        float v = yred[col*17 + r] + yred[(col+64)*17 + r]
                + yred[(col+128)*17 + r] + yred[(col+192)*17 + r] + b1[r];
        v = (v - bm[r]) * rsqrtf(bv[r] + 1e-5f) * bg[r] + bb_[r];
        y[r] = fmaxf(v, 0.f);
    }
    for (int o = g << 6; o < (g << 6) + 64; ++o){
        float s = b2[o];
        #pragma unroll
        for (int r = 0; r < 16; ++r) s += w2s[o*16 + r] * y[r];
        float gg = 1.f / (1.f + __expf(-s)) * 6.103515625e-05f;   // sigmoid * 1/16384
        float xr = xre[base + (size_t)o*NFFT];
        float xi = xim[base + (size_t)o*NFFT];
        xre[base + (size_t)o*NFFT] = gg * xr;
        xim[base + (size_t)o*NFFT] = gg * xi;
    }
}

// ---------- K7: fused ifft2 per image + abs -> PACKED bf16(hi|lo) into re plane ----------
__global__ __launch_bounds__(1024, 8) void k_ifft2_gate(float* re_io, const float* im_){
    __shared__ unsigned sp[128*129];
    int lane = threadIdx.x & 63, wave = threadIdx.x >> 6;
    size_t ib = (size_t)blockIdx.x * NFFT;
    TwI tw; make_twi(tw);
    #pragma unroll 2
    for (int it = 0; it < 8; ++it){
        int jw = (wave << 3) + it;
        size_t base = ib + ((size_t)jw << 7);
        float a0 = re_io[base + lane], b0 = im_[base + lane];
        float a1 = re_io[base + lane + 64], b1 = im_[base + lane + 64];
        dit128t(tw, a0, b0, a1, b1);
        sp[lane*129 + jw]      = packh(a0, b0);
        sp[(lane+64)*129 + jw] = packh(a1, b1);
    }
    __syncthreads();
    #pragma unroll 2
    for (int it = 0; it < 8; ++it){
        int ph = (wave << 3) + it;
        float a0, b0, a1, b1;
        unpackh(sp[ph*129 + lane],      a0, b0);
        unpackh(sp[ph*129 + lane + 64], a1, b1);
        dit128t(tw, a0, b0, a1, b1);
        size_t o = ib + ((size_t)ph << 7);
        re_io[o + lane]      = __uint_as_float(packsplit(sqrtf(a0*a0 + b0*b0)));
        re_io[o + lane + 64] = __uint_as_float(packsplit(sqrtf(a1*a1 + b1*b1)));
    }
}

// ---------- K7b: pack pw into (hi|lo) u32 ----------
__global__ __launch_bounds__(256) void k_pw_cvt(const float* __restrict__ pw, unsigned* __restrict__ pwp){
    int i = (blockIdx.x << 10) + (threadIdx.x << 2);
    float4 v = *(const float4*)(pw + i);
    uint4 o;
    o.x = packsplit(v.x); o.y = packsplit(v.y); o.z = packsplit(v.z); o.w = packsplit(v.w);
    *(uint4*)(pwp + i) = o;
}

// ---------- K8: projection via bf16 MFMA, pre-packed inputs ----------
__global__ __launch_bounds__(256) void k_proj(const unsigned* __restrict__ cat0, const unsigned* __restrict__ cat1,
                                              const unsigned* __restrict__ pwp, float* __restrict__ out){
    __shared__ unsigned As[128*33];   // [o][k] packed, stride 33
    __shared__ unsigned Bs[32*129];   // [k][n] packed, stride 129
    int t = threadIdx.x, lane = t & 63, wave = t >> 6;
    int quad = lane >> 4, l15 = lane & 15;
    int b  = blockIdx.x >> 8;
    int mo = (blockIdx.x >> 7) & 1;
    int nt = blockIdx.x & 127;
    int n0 = nt << 7;
    int wr = (wave >> 1) << 6;
    int wc = (wave & 1) << 6;

    f32x4 acc[4][4];
    #pragma unroll
    for (int i = 0; i < 4; ++i)
        #pragma unroll
        for (int j = 0; j < 4; ++j) acc[i][j] = (f32x4){0.f,0.f,0.f,0.f};

    int ao = t >> 1, ak = (t & 1) << 4;
    int bk = t >> 5, bn = t & 31;

    for (int ks = 0; ks < 16; ++ks){
        int k0 = ks << 5;
        __syncthreads();
        {
            const unsigned* ap = pwp + (size_t)((mo << 7) + ao)*512 + k0 + ak;
            #pragma unroll
            for (int i = 0; i < 16; ++i) As[ao*33 + ak + i] = ap[i];
        }
        {
            #pragma unroll
            for (int p = 0; p < 4; ++p){
                int q = k0 + (p << 3) + bk;
                const unsigned* srow = (q < 256) ? (cat0 + (size_t)((b<<8) + q) * NFFT)
                                                 : (cat1 + (size_t)((b<<8) + (q-256)) * NFFT);
                #pragma unroll
                for (int i = 0; i < 4; ++i){
                    int n = bn + (i << 5);
                    Bs[((p<<3) + bk)*129 + n] = srow[n0 + n];
                }
            }
        }
        __syncthreads();
        FU Ah[4], Al[4], Bh[4], Bl[4];
        #pragma unroll
        for (int mi = 0; mi < 4; ++mi){
            const unsigned* ap = &As[(wr + (mi << 4) + l15)*33 + (quad << 3)];
            #pragma unroll
            for (int p = 0; p < 4; ++p){
                unsigned e0 = ap[2*p], e1 = ap[2*p+1];
                Ah[mi].u[p] = (e0 >> 16) | (e1 & 0xFFFF0000u);
                Al[mi].u[p] = (e0 & 0xFFFFu) | (e1 << 16);
            }
        }
        #pragma unroll
        for (int ni = 0; ni < 4; ++ni){
            int n = wc + (ni << 4) + l15;
            #pragma unroll
            for (int p = 0; p < 4; ++p){
                unsigned e0 = Bs[((quad << 3) + 2*p)*129 + n];
                unsigned e1 = Bs[((quad << 3) + 2*p + 1)*129 + n];
                Bh[ni].u[p] = (e0 >> 16) | (e1 & 0xFFFF0000u);
                Bl[ni].u[p] = (e0 & 0xFFFFu) | (e1 << 16);
            }
        }
        #pragma unroll
        for (int mi = 0; mi < 4; ++mi)
            #pragma unroll
            for (int ni = 0; ni < 4; ++ni){
                acc[mi][ni] = __builtin_amdgcn_mfma_f32_16x16x32_bf16(Ah[mi].v, Bh[ni].v, acc[mi][ni], 0, 0, 0);
                acc[mi][ni] = __builtin_amdgcn_mfma_f32_16x16x32_bf16(Ah[mi].v, Bl[ni].v, acc[mi][ni], 0, 0, 0);
                acc[mi][ni] = __builtin_amdgcn_mfma_f32_16x16x32_bf16(Al[mi].v, Bh[ni].v, acc[mi][ni], 0, 0, 0);
            }
    }
    size_t obase = (size_t)((b << 8) + (mo << 7));
    #pragma unroll
    for (int mi = 0; mi < 4; ++mi)
        #pragma unroll
        for (int ni = 0; ni < 4; ++ni){
            int o_ = wr + (mi << 4) + (quad << 2);
            int n_ = n0 + wc + (ni << 4) + l15;
            float* op = out + (obase + o_)*NFFT + n_;
            #pragma unroll
            for (int r = 0; r < 4; ++r) op[(size_t)r*NFFT] = acc[mi][ni][r];
        }
}

// ---------- host ----------
extern "C" void kernel_launch(void* const* d_in, const int* in_sizes, int n_in,
                              void* d_out, int out_size, void* d_ws, size_t ws_size,
                              hipStream_t stream) {
    const float* x    = (const float*)d_in[0];
    const float* temp = (const float*)d_in[1];
    const float* w1   = (const float*)d_in[2];
    const float* b1   = (const float*)d_in[3];
    const float* bg   = (const float*)d_in[4];
    const float* bb_  = (const float*)d_in[5];
    const float* bm   = (const float*)d_in[6];
    const float* bv   = (const float*)d_in[7];
    const float* w2   = (const float*)d_in[8];
    const float* b2   = (const float*)d_in[9];
    const float* pw   = (const float*)d_in[10];
    float* out = (float*)d_out;

    float* ws = (float*)d_ws;
    float* Are  = ws;            // spectrum re -> gated in-place -> cat1 (packed)
    float* Aim  = ws + NP;       // spectrum im
    float* Ecat = ws + 2*NP;     // Gpart scratch -> mix im -> cat0 (packed, in-place)
    float* norm2 = ws + 3*NP;                  // 1024
    float* G     = norm2 + 1024;               // 65536
    float* attn2 = G + 65536;                  // 65536
    unsigned* pwpack = (unsigned*)(attn2 + 65536);  // 131072
    float* mixre = out;                        // d_out doubles as mix-re scratch
    float* Gpart = Ecat;                       // 1024*2048 floats = 8 MB, dead until k_mix

    size_t need = (3*NP + 1024 + 65536 + 65536 + 131072) * sizeof(float);
    if (ws_size < need) return;

    k_pw_cvt<<<128, 256, 0, stream>>>(pw, pwpack);
    k_fft2_fwd<<<1024, 1024, 0, stream>>>(x, Are, Aim, norm2);
    k_gram<<<1024, 256, 0, stream>>>(Are, Aim, Gpart);
    k_gram_red<<<256, 256, 0, stream>>>(Gpart, G);
    k_attn<<<32, 256, 0, stream>>>(G, norm2, temp, attn2);
    k_mix<<<1024, 256, 0, stream>>>(Are, Aim, attn2, mixre, Ecat);
    k_ifft_n<<<1024, 1024, 0, stream>>>(mixre, Ecat);
    k_gate<<<1024, 256, 0, stream>>>(Are, Aim, w1, b1, bg, bb_, bm, bv, w2, b2);
    k_ifft2_gate<<<1024, 1024, 0, stream>>>(Are, Aim);
    k_proj<<<1024, 256, 0, stream>>>((const unsigned*)Ecat, (const unsigned*)Are, pwpack, out);
    (void)in_sizes; (void)n_in; (void)out_size; (void)ws_size;
}

// Round 4
// 557.671 us; speedup vs baseline: 1.3292x; 1.1357x over previous
//
#include <hip/hip_runtime.h>
#include <math.h>

// Problem constants: b=4, c=256, heads=8, c/head=32, h=w=128, n=16384, cr=16
#define NFFT 16384
static constexpr size_t NP = 16777216; // one plane = 1024 * 16384 floats

typedef short bf16x8 __attribute__((ext_vector_type(8)));
typedef float f32x4  __attribute__((ext_vector_type(4)));
typedef __fp16 h16x2 __attribute__((ext_vector_type(2)));

union FU { bf16x8 v; unsigned u[4]; };

// ---------- helpers ----------
__device__ __forceinline__ void sincos_rev(float rv, float& sn, float& cs){
    sn = __builtin_amdgcn_sinf(rv);   // sin(2*pi*rv)
    cs = __builtin_amdgcn_cosf(rv);
}
__device__ __forceinline__ int rev7(int v){ return (int)(__brev((unsigned)v) >> 25); }

__device__ __forceinline__ unsigned f2bf(float f){
    unsigned u = __float_as_uint(f);
    return (u + 0x7FFFu + ((u >> 16) & 1u)) >> 16;   // round-to-nearest-even
}
__device__ __forceinline__ float bf2f(unsigned h){ return __uint_as_float(h << 16); }
// pack fp32 -> (bf16 hi | bf16 lo) in one u32, stored via float bit-pattern
__device__ __forceinline__ unsigned packsplit(float v){
    unsigned h = f2bf(v);
    float r = v - bf2f(h);
    unsigned l = f2bf(r);
    return (h << 16) | l;
}

// fp16x2 pack/unpack (single u32 per complex value).
union HU2 { h16x2 h; unsigned u; };
__device__ __forceinline__ unsigned packh(float a, float b){
    HU2 z; z.h = __builtin_amdgcn_cvt_pkrtz(a, b); return z.u;
}
__device__ __forceinline__ void unpackh(unsigned u, float& a, float& b){
    HU2 z; z.u = u; a = (float)z.h.x; b = (float)z.h.y;
}

// ---------- sign/identity-folded per-lane twiddles ----------
struct TwF { float cw[6], sw[6], sg[6], c6, s6; };
__device__ __forceinline__ void make_twf(TwF& t){
    const int l = threadIdx.x & 63;
    #pragma unroll
    for (int lg = 0; lg < 6; ++lg){
        int m = 1 << lg;
        bool up = (l & m) != 0;
        int e = (l & (m-1)) * (64 >> lg);
        float sn, cs; sincos_rev((float)e * 0.0078125f, sn, cs);
        t.cw[lg] = up ? cs : 1.f;
        t.sw[lg] = up ? -sn : 0.f;
        t.sg[lg] = up ? -1.f : 1.f;
    }
    sincos_rev((float)l * 0.0078125f, t.s6, t.c6);
}
struct TwI { float cw[6], sw[6], c6, s6; };
__device__ __forceinline__ void make_twi(TwI& t){
    const int l = threadIdx.x & 63;
    #pragma unroll
    for (int lg = 0; lg < 6; ++lg){
        int m = 1 << lg;
        bool up = (l & m) != 0;
        int e = (l & (m-1)) * (64 >> lg);
        float sn, cs; sincos_rev((float)e * 0.0078125f, sn, cs);
        t.cw[lg] = up ? -cs : cs;
        t.sw[lg] = up ? -sn : sn;
    }
    sincos_rev((float)l * 0.0078125f, t.s6, t.c6);
}

// DIF forward: natural in, slot j holds X[rev7(j)] out. W = e^{-2pi i/128}
__device__ __forceinline__ void dif128t(const TwF& t, float& r0, float& i0, float& r1, float& i1){
    {
        float ar = r0 + r1, ai = i0 + i1;
        float br = r0 - r1, bi = i0 - i1;
        r0 = ar; i0 = ai;
        r1 =  br*t.c6 + bi*t.s6;
        i1 = -br*t.s6 + bi*t.c6;
    }
    #pragma unroll
    for (int lg = 5; lg >= 0; --lg){
        int m = 1 << lg;
        float cw = t.cw[lg], sw = t.sw[lg], sg = t.sg[lg];
        float pr = __shfl_xor(r0, m, 64), pi = __shfl_xor(i0, m, 64);
        float tr = fmaf(sg, r0, pr), ti = fmaf(sg, i0, pi);
        r0 = tr*cw - ti*sw;
        i0 = tr*sw + ti*cw;
        pr = __shfl_xor(r1, m, 64); pi = __shfl_xor(i1, m, 64);
        tr = fmaf(sg, r1, pr); ti = fmaf(sg, i1, pi);
        r1 = tr*cw - ti*sw;
        i1 = tr*sw + ti*cw;
    }
}

// DIT inverse (unnormalized): slot j holds X[rev7(j)] in, natural out. W = e^{+2pi i/128}
__device__ __forceinline__ void dit128t(const TwI& t, float& r0, float& i0, float& r1, float& i1){
    const int l = threadIdx.x & 63;
    #pragma unroll
    for (int lg = 0; lg <= 5; ++lg){
        int m = 1 << lg;
        bool up = (l & m) != 0;
        float cw = t.cw[lg], sw = t.sw[lg];
        float pr = __shfl_xor(r0, m, 64), pi = __shfl_xor(i0, m, 64);
        float vr = up ? r0 : pr, vi = up ? i0 : pi;
        float ar = up ? pr : r0, ai = up ? pi : i0;
        r0 = fmaf(vr, cw, fmaf(vi, -sw, ar));
        i0 = fmaf(vr, sw, fmaf(vi,  cw, ai));
        pr = __shfl_xor(r1, m, 64); pi = __shfl_xor(i1, m, 64);
        vr = up ? r1 : pr; vi = up ? i1 : pi;
        ar = up ? pr : r1; ai = up ? pi : i1;
        r1 = fmaf(vr, cw, fmaf(vi, -sw, ar));
        i1 = fmaf(vr, sw, fmaf(vi,  cw, ai));
    }
    {
        float wr = r1*t.c6 - i1*t.s6, wi = r1*t.s6 + i1*t.c6;
        float ar = r0 + wr, ai = i0 + wi;
        r1 = r0 - wr; i1 = i0 - wi;
        r0 = ar; i0 = ai;
    }
}

// ---------- K1: fused forward fft2 per image, 1024 threads ----------
__global__ __launch_bounds__(1024, 8) void k_fft2_fwd(const float* __restrict__ x,
                                                   float* __restrict__ ore, float* __restrict__ oim,
                                                   float* __restrict__ norm2){
    __shared__ unsigned sp[128*129];
    __shared__ float red[16];
    int lane = threadIdx.x & 63, wave = threadIdx.x >> 6;
    int img = blockIdx.x;
    TwF tw; make_twf(tw);
    const float* base = x + (size_t)img * NFFT;
    #pragma unroll 2
    for (int it = 0; it < 8; ++it){
        int h = (wave << 3) + it;
        float a0 = base[h*128 + lane], b0 = 0.f;
        float a1 = base[h*128 + lane + 64], b1 = 0.f;
        dif128t(tw, a0, b0, a1, b1);
        sp[lane*129 + h]      = packh(a0, b0);
        sp[(lane+64)*129 + h] = packh(a1, b1);
    }
    __syncthreads();
    float acc = 0.f;
    #pragma unroll 2
    for (int it = 0; it < 8; ++it){
        int j = (wave << 3) + it;
        float a0, b0, a1, b1;
        unpackh(sp[j*129 + lane],      a0, b0);
        unpackh(sp[j*129 + lane + 64], a1, b1);
        dif128t(tw, a0, b0, a1, b1);
        size_t o = (size_t)img*NFFT + (size_t)j*128;
        ore[o + lane] = a0;      oim[o + lane] = b0;
        ore[o + lane + 64] = a1; oim[o + lane + 64] = b1;
        acc += a0*a0 + b0*b0 + a1*a1 + b1*b1;
    }
    #pragma unroll
    for (int m = 32; m >= 1; m >>= 1) acc += __shfl_xor(acc, m, 64);
    if (lane == 0) red[wave] = acc;
    __syncthreads();
    if (threadIdx.x == 0){
        float s = 0.f;
        #pragma unroll
        for (int i = 0; i < 16; ++i) s += red[i];
        norm2[img] = s;
    }
}

// ---------- K2: gram via bf16 MFMA ----------
__global__ __launch_bounds__(256) void k_gram(const float* __restrict__ xre, const float* __restrict__ xim,
                                              float* __restrict__ Gpart){
    __shared__ unsigned lds[2*32*132];   // 2 planes x 32 ch x 132 u32 (2 bf16/u32)
    int t = threadIdx.x, lane = t & 63, wave = t >> 6;
    int bh = blockIdx.x >> 5;          // 32
    int ks = blockIdx.x & 31;          // 32 k-splits, K=512 each
    size_t cbase = (size_t)bh * 32 * NFFT;
    int k0blk = ks << 9;

    int sc  = t >> 3;        // staging channel 0..31
    int sk4 = (t & 7) << 2;  // within-32-float chunk offset

    f32x4 aRe[2][2], aIm[2][2];
    #pragma unroll
    for (int i = 0; i < 2; ++i)
        #pragma unroll
        for (int j = 0; j < 2; ++j){ aRe[i][j] = (f32x4){0,0,0,0}; aIm[i][j] = (f32x4){0,0,0,0}; }

    for (int tile = 0; tile < 2; ++tile){
        int kb = k0blk + (tile << 8);
        __syncthreads();
        {
            const float* pr  = xre + cbase + (size_t)sc*NFFT + kb + sk4;
            const float* pi_ = xim + cbase + (size_t)sc*NFFT + kb + sk4;
            unsigned* dr = &lds[ sc*132 + (sk4 >> 1) ];
            unsigned* di = &lds[ 32*132 + sc*132 + (sk4 >> 1) ];
            #pragma unroll
            for (int i = 0; i < 8; ++i){
                float4 v = *(const float4*)(pr + (i << 5));
                dr[(i<<4)]     = f2bf(v.x) | (f2bf(v.y) << 16);
                dr[(i<<4) + 1] = f2bf(v.z) | (f2bf(v.w) << 16);
                v = *(const float4*)(pi_ + (i << 5));
                di[(i<<4)]     = f2bf(v.x) | (f2bf(v.y) << 16);
                di[(i<<4) + 1] = f2bf(v.z) | (f2bf(v.w) << 16);
            }
        }
        __syncthreads();
        #pragma unroll
        for (int ss = 0; ss < 2; ++ss){
            int s = wave + (ss << 2);
            int kbase = (s << 4) + ((lane >> 4) << 2);
            FU fr0, fr1, fi0, fi1, fn0, fn1;
            *(uint4*)fr0.u = *(const uint4*)&lds[ (lane & 15)*132 + kbase ];
            *(uint4*)fr1.u = *(const uint4*)&lds[ ((lane & 15) + 16)*132 + kbase ];
            *(uint4*)fi0.u = *(const uint4*)&lds[ 32*132 + (lane & 15)*132 + kbase ];
            *(uint4*)fi1.u = *(const uint4*)&lds[ 32*132 + ((lane & 15) + 16)*132 + kbase ];
            #pragma unroll
            for (int p = 0; p < 4; ++p){ fn0.u[p] = fi0.u[p] ^ 0x80008000u; fn1.u[p] = fi1.u[p] ^ 0x80008000u; }
            aRe[0][0] = __builtin_amdgcn_mfma_f32_16x16x32_bf16(fr0.v, fr0.v, aRe[0][0], 0, 0, 0);
            aRe[0][0] = __builtin_amdgcn_mfma_f32_16x16x32_bf16(fn0.v, fi0.v, aRe[0][0], 0, 0, 0);
            aRe[0][1] = __builtin_amdgcn_mfma_f32_16x16x32_bf16(fr0.v, fr1.v, aRe[0][1], 0, 0, 0);
            aRe[0][1] = __builtin_amdgcn_mfma_f32_16x16x32_bf16(fn0.v, fi1.v, aRe[0][1], 0, 0, 0);
            aRe[1][0] = __builtin_amdgcn_mfma_f32_16x16x32_bf16(fr1.v, fr0.v, aRe[1][0], 0, 0, 0);
            aRe[1][0] = __builtin_amdgcn_mfma_f32_16x16x32_bf16(fn1.v, fi0.v, aRe[1][0], 0, 0, 0);
            aRe[1][1] = __builtin_amdgcn_mfma_f32_16x16x32_bf16(fr1.v, fr1.v, aRe[1][1], 0, 0, 0);
            aRe[1][1] = __builtin_amdgcn_mfma_f32_16x16x32_bf16(fn1.v, fi1.v, aRe[1][1], 0, 0, 0);
            aIm[0][0] = __builtin_amdgcn_mfma_f32_16x16x32_bf16(fr0.v, fi0.v, aIm[0][0], 0, 0, 0);
            aIm[0][0] = __builtin_amdgcn_mfma_f32_16x16x32_bf16(fi0.v, fr0.v, aIm[0][0], 0, 0, 0);
            aIm[0][1] = __builtin_amdgcn_mfma_f32_16x16x32_bf16(fr0.v, fi1.v, aIm[0][1], 0, 0, 0);
            aIm[0][1] = __builtin_amdgcn_mfma_f32_16x16x32_bf16(fi0.v, fr1.v, aIm[0][1], 0, 0, 0);
            aIm[1][0] = __builtin_amdgcn_mfma_f32_16x16x32_bf16(fr1.v, fi0.v, aIm[1][0], 0, 0, 0);
            aIm[1][0] = __builtin_amdgcn_mfma_f32_16x16x32_bf16(fi1.v, fr0.v, aIm[1][0], 0, 0, 0);
            aIm[1][1] = __builtin_amdgcn_mfma_f32_16x16x32_bf16(fr1.v, fi1.v, aIm[1][1], 0, 0, 0);
            aIm[1][1] = __builtin_amdgcn_mfma_f32_16x16x32_bf16(fi1.v, fr1.v, aIm[1][1], 0, 0, 0);
        }
    }
    __syncthreads();
    float* rbuf = (float*)lds;
    int dcol = lane & 15, rrow = lane >> 4;
    #pragma unroll
    for (int i = 0; i < 2; ++i)
        #pragma unroll
        for (int j = 0; j < 2; ++j)
            #pragma unroll
            for (int r = 0; r < 4; ++r){
                int c = (i << 4) + (rrow << 2) + r;
                int d = (j << 4) + dcol;
                rbuf[wave*2048 + ((c << 5) + d)*2    ] = aRe[i][j][r];
                rbuf[wave*2048 + ((c << 5) + d)*2 + 1] = aIm[i][j][r];
            }
    __syncthreads();
    float* gp = Gpart + (size_t)blockIdx.x * 2048;
    for (int idx = t; idx < 2048; idx += 256)
        gp[idx] = rbuf[idx] + rbuf[2048 + idx] + rbuf[4096 + idx] + rbuf[6144 + idx];
}

// ---------- K2b: reduce 32 k-split partials per bh ----------
__global__ __launch_bounds__(256) void k_gram_red(const float* __restrict__ Gpart, float* __restrict__ G){
    int bh = blockIdx.x >> 3;
    int q  = ((blockIdx.x & 7) << 8) + threadIdx.x;
    const float* gp = Gpart + (size_t)bh * 32 * 2048 + q;
    float s = 0.f;
    #pragma unroll 8
    for (int p = 0; p < 32; ++p) s += gp[(size_t)p * 2048];
    G[(size_t)bh * 2048 + q] = s;
}

// ---------- K3: normalize, temperature, complex softmax, fold IF32 * (1/524288) ----------
__global__ __launch_bounds__(256) void k_attn(const float* __restrict__ G, const float* __restrict__ norm2,
                                              const float* __restrict__ temp, float* __restrict__ attn2){
    __shared__ float ar[32*33], ai[32*33];
    int bh = blockIdx.x, h = bh & 7, t = threadIdx.x;
    if (t < 32){
        float tv = temp[h];
        float nc = fmaxf(sqrtf(norm2[(bh<<5) + t]), 1e-12f);
        const float* gr = G + (size_t)bh*2048 + t*64;
        float mr = -1e30f, mi = -1e30f;
        for (int d = 0; d < 32; ++d){
            float nd = fmaxf(sqrtf(norm2[(bh<<5) + d]), 1e-12f);
            float s = tv / (nc * nd);
            float vr = gr[d*2] * s, vi = gr[d*2+1] * s;
            ar[t*33+d] = vr; ai[t*33+d] = vi;
            mr = fmaxf(mr, vr); mi = fmaxf(mi, vi);
        }
        float sr = 0.f, si = 0.f;
        for (int d = 0; d < 32; ++d){
            float er = __expf(ar[t*33+d] - mr), ei = __expf(ai[t*33+d] - mi);
            ar[t*33+d] = er; ai[t*33+d] = ei; sr += er; si += ei;
        }
        sr = 1.f/sr; si = 1.f/si;
        for (int d = 0; d < 32; ++d){ ar[t*33+d] *= sr; ai[t*33+d] *= si; }
    }
    __syncthreads();
    const float S = 1.f / 524288.f;
    for (int q = t; q < 1024; q += 256){
        int e = q >> 5, d = q & 31;
        float sr = 0.f, si = 0.f;
        for (int c = 0; c < 32; ++c){
            float sn, cs; sincos_rev((float)((e*c) & 31) * 0.03125f, sn, cs);
            float xr = ar[c*33+d], xi = ai[c*33+d];
            sr += cs*xr - sn*xi;
            si += cs*xi + sn*xr;
        }
        attn2[(size_t)bh*2048 + q*2]     = sr * S;
        attn2[(size_t)bh*2048 + q*2 + 1] = si * S;
    }
}

// ---------- K4: mix[e][n] = sum_d attn2[e][d] * X[d][n] via bf16 MFMA ----------
// K=32 (=d) fits one mfma_16x16x32. A (attn2) pre-built as split-bf16 frags in regs;
// X staged as packsplit u32 in LDS, B-frags assembled with k_proj's bit-merge.
// Output written as fp16-packed complex (re|im in one u32) for k_ifft_n.
__global__ __launch_bounds__(256) void k_mix(const float* __restrict__ xre, const float* __restrict__ xim,
                                             const float* __restrict__ attn2,
                                             unsigned* __restrict__ om){
    __shared__ unsigned lds[2*32*65];   // [plane][d][col 0..64] packsplit u32; a2 staging at start
    int t = threadIdx.x, lane = t & 63, wave = t >> 6;
    int quad = lane >> 4, l15 = lane & 15;
    int bh = blockIdx.x >> 5;
    int n0 = (blockIdx.x & 31) << 9;
    size_t cbase = (size_t)bh * 32 * NFFT;

    {   // load attn2 into LDS (reusing staging space)
        const float4* s4 = (const float4*)(attn2 + (size_t)bh*2048);
        float4* d4 = (float4*)lds;
        d4[t] = s4[t]; d4[t + 256] = s4[t + 256];
    }
    __syncthreads();
    // build split-bf16 A fragments: lane holds A[row=l15(+16*et)][k=quad*8+i]
    FU ArH[2], ArL[2], AiH[2], AiL[2];
    {
        const float* a2 = (const float*)lds;
        #pragma unroll
        for (int et = 0; et < 2; ++et){
            int e = (et << 4) + l15;
            #pragma unroll
            for (int p = 0; p < 4; ++p){
                int d0 = (quad << 3) + (p << 1);
                float re0 = a2[(e*32 + d0)*2],       im0 = a2[(e*32 + d0)*2 + 1];
                float re1 = a2[(e*32 + d0 + 1)*2],   im1 = a2[(e*32 + d0 + 1)*2 + 1];
                unsigned h0 = f2bf(re0), h1 = f2bf(re1);
                ArH[et].u[p] = h0 | (h1 << 16);
                ArL[et].u[p] = f2bf(re0 - bf2f(h0)) | (f2bf(re1 - bf2f(h1)) << 16);
                h0 = f2bf(im0); h1 = f2bf(im1);
                AiH[et].u[p] = h0 | (h1 << 16);
                AiL[et].u[p] = f2bf(im0 - bf2f(h0)) | (f2bf(im1 - bf2f(h1)) << 16);
            }
        }
    }
    __syncthreads();

    int sd = t >> 3, sc8 = (t & 7) << 3;   // staging: row d = t>>3, 8 cols at (t&7)*8
    for (int tile = 0; tile < 8; ++tile){
        int nb = n0 + (tile << 6);
        {   // stage X[32][64] re+im as packsplit
            const float* pr  = xre + cbase + (size_t)sd*NFFT + nb + sc8;
            const float* pi_ = xim + cbase + (size_t)sd*NFFT + nb + sc8;
            unsigned* dr = &lds[sd*65 + sc8];
            unsigned* di = &lds[32*65 + sd*65 + sc8];
            float4 v0 = *(const float4*)pr, v1 = *(const float4*)(pr + 4);
            dr[0]=packsplit(v0.x); dr[1]=packsplit(v0.y); dr[2]=packsplit(v0.z); dr[3]=packsplit(v0.w);
            dr[4]=packsplit(v1.x); dr[5]=packsplit(v1.y); dr[6]=packsplit(v1.z); dr[7]=packsplit(v1.w);
            v0 = *(const float4*)pi_; v1 = *(const float4*)(pi_ + 4);
            di[0]=packsplit(v0.x); di[1]=packsplit(v0.y); di[2]=packsplit(v0.z); di[3]=packsplit(v0.w);
            di[4]=packsplit(v1.x); di[5]=packsplit(v1.y); di[6]=packsplit(v1.z); di[7]=packsplit(v1.w);
        }
        __syncthreads();
        // each wave computes 16 cols at nb + wave*16
        int colb = (wave << 4) + l15;
        FU XrH, XrL, XiH, XiL, XnH, XnL;
        #pragma unroll
        for (int p = 0; p < 4; ++p){
            int k0 = (quad << 3) + (p << 1);
            unsigned e0 = lds[k0*65 + colb], e1 = lds[(k0+1)*65 + colb];
            XrH.u[p] = (e0 >> 16) | (e1 & 0xFFFF0000u);
            XrL.u[p] = (e0 & 0xFFFFu) | (e1 << 16);
            e0 = lds[32*65 + k0*65 + colb]; e1 = lds[32*65 + (k0+1)*65 + colb];
            XiH.u[p] = (e0 >> 16) | (e1 & 0xFFFF0000u);
            XiL.u[p] = (e0 & 0xFFFFu) | (e1 << 16);
            XnH.u[p] = XiH.u[p] ^ 0x80008000u;
            XnL.u[p] = XiL.u[p] ^ 0x80008000u;
        }
        #pragma unroll
        for (int et = 0; et < 2; ++et){
            f32x4 ar = (f32x4){0,0,0,0}, ai = (f32x4){0,0,0,0};
            ar = __builtin_amdgcn_mfma_f32_16x16x32_bf16(ArH[et].v, XrH.v, ar, 0, 0, 0);
            ar = __builtin_amdgcn_mfma_f32_16x16x32_bf16(ArH[et].v, XrL.v, ar, 0, 0, 0);
            ar = __builtin_amdgcn_mfma_f32_16x16x32_bf16(ArL[et].v, XrH.v, ar, 0, 0, 0);
            ar = __builtin_amdgcn_mfma_f32_16x16x32_bf16(AiH[et].v, XnH.v, ar, 0, 0, 0);
            ar = __builtin_amdgcn_mfma_f32_16x16x32_bf16(AiH[et].v, XnL.v, ar, 0, 0, 0);
            ar = __builtin_amdgcn_mfma_f32_16x16x32_bf16(AiL[et].v, XnH.v, ar, 0, 0, 0);
            ai = __builtin_amdgcn_mfma_f32_16x16x32_bf16(ArH[et].v, XiH.v, ai, 0, 0, 0);
            ai = __builtin_amdgcn_mfma_f32_16x16x32_bf16(ArH[et].v, XiL.v, ai, 0, 0, 0);
            ai = __builtin_amdgcn_mfma_f32_16x16x32_bf16(ArL[et].v, XiH.v, ai, 0, 0, 0);
            ai = __builtin_amdgcn_mfma_f32_16x16x32_bf16(AiH[et].v, XrH.v, ai, 0, 0, 0);
            ai = __builtin_amdgcn_mfma_f32_16x16x32_bf16(AiH[et].v, XrL.v, ai, 0, 0, 0);
            ai = __builtin_amdgcn_mfma_f32_16x16x32_bf16(AiL[et].v, XrH.v, ai, 0, 0, 0);
            // D map: row e = et*16 + quad*4 + r, col = colb
            #pragma unroll
            for (int r = 0; r < 4; ++r){
                int e = (et << 4) + (quad << 2) + r;
                om[cbase + (size_t)e*NFFT + nb + colb] = packh(ar[r], ai[r]);
            }
        }
        __syncthreads();
    }
}

// ---------- K5: fused 16384-pt inverse FFT + abs per row; fp16-packed complex in, bf16(hi|lo) out ----------
__global__ __launch_bounds__(1024, 8) void k_ifft_n(unsigned* io){
    __shared__ unsigned sp[128*129];
    int lane = threadIdx.x & 63, wave = threadIdx.x >> 6;
    size_t rb = (size_t)blockIdx.x * NFFT;
    TwI tw; make_twi(tw);
    #pragma unroll 2
    for (int it = 0; it < 8; ++it){
        int jw = (wave << 3) + it;
        size_t base = rb + ((size_t)jw << 7);
        float a0, b0, a1, b1;
        unpackh(io[base + lane], a0, b0);
        unpackh(io[base + lane + 64], a1, b1);
        dit128t(tw, a0, b0, a1, b1);
        int kw = rev7(jw);
        float sn, cs;
        sincos_rev((float)(lane * kw) * 6.103515625e-05f, sn, cs);
        float r = a0*cs - b0*sn, i2 = a0*sn + b0*cs;
        sp[lane*129 + jw] = packh(r, i2);
        sincos_rev((float)((lane + 64) * kw) * 6.103515625e-05f, sn, cs);
        r = a1*cs - b1*sn; i2 = a1*sn + b1*cs;
        sp[(lane+64)*129 + jw] = packh(r, i2);
    }
    __syncthreads();
    unsigned av[8][2];
    #pragma unroll 2
    for (int it = 0; it < 8; ++it){
        int pw = (wave << 3) + it;
        float a0, b0, a1, b1;
        unpackh(sp[pw*129 + lane],      a0, b0);
        unpackh(sp[pw*129 + lane + 64], a1, b1);
        dit128t(tw, a0, b0, a1, b1);
        av[it][0] = packsplit(sqrtf(a0*a0 + b0*b0));
        av[it][1] = packsplit(sqrtf(a1*a1 + b1*b1));
    }
    __syncthreads();
    #pragma unroll 2
    for (int it = 0; it < 8; ++it){
        int pw = (wave << 3) + it;
        sp[lane*129 + pw] = av[it][0];
        sp[(lane+64)*129 + pw] = av[it][1];
    }
    __syncthreads();
    int row = threadIdx.x >> 3, cb = (threadIdx.x & 7) << 4;
    size_t ob = rb + ((size_t)row << 7) + cb;
    const unsigned* s = &sp[row*129 + cb];
    #pragma unroll
    for (int q = 0; q < 4; ++q)
        *(uint4*)(io + ob + (q << 2)) = make_uint4(s[q*4], s[q*4+1], s[q*4+2], s[q*4+3]);
}

// ---------- K6: gating, IN-PLACE, 4-way split for occupancy ----------
__global__ __launch_bounds__(256) void k_gate(float* xre, float* xim,
                                              const float* __restrict__ w1, const float* __restrict__ b1,
                                              const float* __restrict__ bg, const float* __restrict__ bb_,
                                              const float* __restrict__ bm, const float* __restrict__ bv,
                                              const float* __restrict__ w2, const float* __restrict__ b2){
    __shared__ float w1T[256*17];
    __shared__ float w2s[256*16];
    __shared__ float yred[256*17];
    int t = threadIdx.x, g = t >> 6, col = t & 63;
    #pragma unroll
    for (int i = 0; i < 16; ++i) w1T[t*17 + i] = w1[i*256 + t];
    {
        const float4* s4 = (const float4*)w2; float4* d4 = (float4*)w2s;
        #pragma unroll
        for (int i = 0; i < 4; ++i) d4[i*256 + t] = s4[i*256 + t];
    }
    __syncthreads();
    int b = blockIdx.x >> 8;
    int n = ((blockIdx.x & 255) << 6) + col;
    size_t base = ((size_t)b << 8) * NFFT + n;
    float y[16];
    #pragma unroll
    for (int r = 0; r < 16; ++r) y[r] = 0.f;
    for (int c = g << 6; c < (g << 6) + 64; ++c){
        float xr = xre[base + (size_t)c*NFFT];
        #pragma unroll
        for (int r = 0; r < 16; ++r) y[r] += w1T[c*17 + r] * xr;
    }
    #pragma unroll
    for (int r = 0; r < 16; ++r) yred[t*17 + r] = y[r];
    __syncthreads();
    #pragma unroll
    for (int r = 0; r < 16; ++r){
        float v = yred[col*17 + r] + yred[(col+64)*17 + r]
                + yred[(col+128)*17 + r] + yred[(col+192)*17 + r] + b1[r];
        v = (v - bm[r]) * rsqrtf(bv[r] + 1e-5f) * bg[r] + bb_[r];
        y[r] = fmaxf(v, 0.f);
    }
    for (int o = g << 6; o < (g << 6) + 64; ++o){
        float s = b2[o];
        #pragma unroll
        for (int r = 0; r < 16; ++r) s += w2s[o*16 + r] * y[r];
        float gg = 1.f / (1.f + __expf(-s)) * 6.103515625e-05f;   // sigmoid * 1/16384
        float xr = xre[base + (size_t)o*NFFT];
        float xi = xim[base + (size_t)o*NFFT];
        xre[base + (size_t)o*NFFT] = gg * xr;
        xim[base + (size_t)o*NFFT] = gg * xi;
    }
}

// ---------- K7: fused ifft2 per image + abs -> PACKED bf16(hi|lo) into re plane ----------
__global__ __launch_bounds__(1024, 8) void k_ifft2_gate(float* re_io, const float* im_){
    __shared__ unsigned sp[128*129];
    int lane = threadIdx.x & 63, wave = threadIdx.x >> 6;
    size_t ib = (size_t)blockIdx.x * NFFT;
    TwI tw; make_twi(tw);
    #pragma unroll 2
    for (int it = 0; it < 8; ++it){
        int jw = (wave << 3) + it;
        size_t base = ib + ((size_t)jw << 7);
        float a0 = re_io[base + lane], b0 = im_[base + lane];
        float a1 = re_io[base + lane + 64], b1 = im_[base + lane + 64];
        dit128t(tw, a0, b0, a1, b1);
        sp[lane*129 + jw]      = packh(a0, b0);
        sp[(lane+64)*129 + jw] = packh(a1, b1);
    }
    __syncthreads();
    #pragma unroll 2
    for (int it = 0; it < 8; ++it){
        int ph = (wave << 3) + it;
        float a0, b0, a1, b1;
        unpackh(sp[ph*129 + lane],      a0, b0);
        unpackh(sp[ph*129 + lane + 64], a1, b1);
        dit128t(tw, a0, b0, a1, b1);
        size_t o = ib + ((size_t)ph << 7);
        re_io[o + lane]      = __uint_as_float(packsplit(sqrtf(a0*a0 + b0*b0)));
        re_io[o + lane + 64] = __uint_as_float(packsplit(sqrtf(a1*a1 + b1*b1)));
    }
}

// ---------- K7b: pack pw into (hi|lo) u32 ----------
__global__ __launch_bounds__(256) void k_pw_cvt(const float* __restrict__ pw, unsigned* __restrict__ pwp){
    int i = (blockIdx.x << 10) + (threadIdx.x << 2);
    float4 v = *(const float4*)(pw + i);
    uint4 o;
    o.x = packsplit(v.x); o.y = packsplit(v.y); o.z = packsplit(v.z); o.w = packsplit(v.w);
    *(uint4*)(pwp + i) = o;
}

// ---------- K8: projection via bf16 MFMA, pre-packed inputs ----------
__global__ __launch_bounds__(256) void k_proj(const unsigned* __restrict__ cat0, const unsigned* __restrict__ cat1,
                                              const unsigned* __restrict__ pwp, float* __restrict__ out){
    __shared__ unsigned As[128*33];   // [o][k] packed, stride 33
    __shared__ unsigned Bs[32*129];   // [k][n] packed, stride 129
    int t = threadIdx.x, lane = t & 63, wave = t >> 6;
    int quad = lane >> 4, l15 = lane & 15;
    int b  = blockIdx.x >> 8;
    int mo = (blockIdx.x >> 7) & 1;
    int nt = blockIdx.x & 127;
    int n0 = nt << 7;
    int wr = (wave >> 1) << 6;
    int wc = (wave & 1) << 6;

    f32x4 acc[4][4];
    #pragma unroll
    for (int i = 0; i < 4; ++i)
        #pragma unroll
        for (int j = 0; j < 4; ++j) acc[i][j] = (f32x4){0.f,0.f,0.f,0.f};

    int ao = t >> 1, ak = (t & 1) << 4;
    int bk = t >> 5, bn = t & 31;

    for (int ks = 0; ks < 16; ++ks){
        int k0 = ks << 5;
        __syncthreads();
        {
            const unsigned* ap = pwp + (size_t)((mo << 7) + ao)*512 + k0 + ak;
            #pragma unroll
            for (int i = 0; i < 16; ++i) As[ao*33 + ak + i] = ap[i];
        }
        {
            #pragma unroll
            for (int p = 0; p < 4; ++p){
                int q = k0 + (p << 3) + bk;
                const unsigned* srow = (q < 256) ? (cat0 + (size_t)((b<<8) + q) * NFFT)
                                                 : (cat1 + (size_t)((b<<8) + (q-256)) * NFFT);
                #pragma unroll
                for (int i = 0; i < 4; ++i){
                    int n = bn + (i << 5);
                    Bs[((p<<3) + bk)*129 + n] = srow[n0 + n];
                }
            }
        }
        __syncthreads();
        FU Ah[4], Al[4], Bh[4], Bl[4];
        #pragma unroll
        for (int mi = 0; mi < 4; ++mi){
            const unsigned* ap = &As[(wr + (mi << 4) + l15)*33 + (quad << 3)];
            #pragma unroll
            for (int p = 0; p < 4; ++p){
                unsigned e0 = ap[2*p], e1 = ap[2*p+1];
                Ah[mi].u[p] = (e0 >> 16) | (e1 & 0xFFFF0000u);
                Al[mi].u[p] = (e0 & 0xFFFFu) | (e1 << 16);
            }
        }
        #pragma unroll
        for (int ni = 0; ni < 4; ++ni){
            int n = wc + (ni << 4) + l15;
            #pragma unroll
            for (int p = 0; p < 4; ++p){
                unsigned e0 = Bs[((quad << 3) + 2*p)*129 + n];
                unsigned e1 = Bs[((quad << 3) + 2*p + 1)*129 + n];
                Bh[ni].u[p] = (e0 >> 16) | (e1 & 0xFFFF0000u);
                Bl[ni].u[p] = (e0 & 0xFFFFu) | (e1 << 16);
            }
        }
        #pragma unroll
        for (int mi = 0; mi < 4; ++mi)
            #pragma unroll
            for (int ni = 0; ni < 4; ++ni){
                acc[mi][ni] = __builtin_amdgcn_mfma_f32_16x16x32_bf16(Ah[mi].v, Bh[ni].v, acc[mi][ni], 0, 0, 0);
                acc[mi][ni] = __builtin_amdgcn_mfma_f32_16x16x32_bf16(Ah[mi].v, Bl[ni].v, acc[mi][ni], 0, 0, 0);
                acc[mi][ni] = __builtin_amdgcn_mfma_f32_16x16x32_bf16(Al[mi].v, Bh[ni].v, acc[mi][ni], 0, 0, 0);
            }
    }
    size_t obase = (size_t)((b << 8) + (mo << 7));
    #pragma unroll
    for (int mi = 0; mi < 4; ++mi)
        #pragma unroll
        for (int ni = 0; ni < 4; ++ni){
            int o_ = wr + (mi << 4) + (quad << 2);
            int n_ = n0 + wc + (ni << 4) + l15;
            float* op = out + (obase + o_)*NFFT + n_;
            #pragma unroll
            for (int r = 0; r < 4; ++r) op[(size_t)r*NFFT] = acc[mi][ni][r];
        }
}

// ---------- host ----------
extern "C" void kernel_launch(void* const* d_in, const int* in_sizes, int n_in,
                              void* d_out, int out_size, void* d_ws, size_t ws_size,
                              hipStream_t stream) {
    const float* x    = (const float*)d_in[0];
    const float* temp = (const float*)d_in[1];
    const float* w1   = (const float*)d_in[2];
    const float* b1   = (const float*)d_in[3];
    const float* bg   = (const float*)d_in[4];
    const float* bb_  = (const float*)d_in[5];
    const float* bm   = (const float*)d_in[6];
    const float* bv   = (const float*)d_in[7];
    const float* w2   = (const float*)d_in[8];
    const float* b2   = (const float*)d_in[9];
    const float* pw   = (const float*)d_in[10];
    float* out = (float*)d_out;

    float* ws = (float*)d_ws;
    float* Are  = ws;            // spectrum re -> gated in-place -> cat1 (packed)
    float* Aim  = ws + NP;       // spectrum im
    float* Ecat = ws + 2*NP;     // Gpart scratch -> mix (fp16 packed) -> cat0 (packed, in-place)
    float* norm2 = ws + 3*NP;                  // 1024
    float* G     = norm2 + 1024;               // 65536
    float* attn2 = G + 65536;                  // 65536
    unsigned* pwpack = (unsigned*)(attn2 + 65536);  // 131072
    float* Gpart = Ecat;                       // 1024*2048 floats = 8 MB, dead until k_mix

    size_t need = (3*NP + 1024 + 65536 + 65536 + 131072) * sizeof(float);
    if (ws_size < need) return;

    k_pw_cvt<<<128, 256, 0, stream>>>(pw, pwpack);
    k_fft2_fwd<<<1024, 1024, 0, stream>>>(x, Are, Aim, norm2);
    k_gram<<<1024, 256, 0, stream>>>(Are, Aim, Gpart);
    k_gram_red<<<256, 256, 0, stream>>>(Gpart, G);
    k_attn<<<32, 256, 0, stream>>>(G, norm2, temp, attn2);
    k_mix<<<1024, 256, 0, stream>>>(Are, Aim, attn2, (unsigned*)Ecat);
    k_ifft_n<<<1024, 1024, 0, stream>>>((unsigned*)Ecat);
    k_gate<<<1024, 256, 0, stream>>>(Are, Aim, w1, b1, bg, bb_, bm, bv, w2, b2);
    k_ifft2_gate<<<1024, 1024, 0, stream>>>(Are, Aim);
    k_proj<<<1024, 256, 0, stream>>>((const unsigned*)Ecat, (const unsigned*)Are, pwpack, out);
    (void)in_sizes; (void)n_in; (void)out_size; (void)ws_size;
}

// Round 6
// 518.588 us; speedup vs baseline: 1.4294x; 1.0754x over previous
//
#include <hip/hip_runtime.h>
#include <math.h>

// Problem constants: b=4, c=256, heads=8, c/head=32, h=w=128, n=16384, cr=16
#define NFFT 16384
static constexpr size_t NP = 16777216; // one fp32 plane = 1024 * 16384 floats

typedef short bf16x8 __attribute__((ext_vector_type(8)));
typedef __fp16 f16x8 __attribute__((ext_vector_type(8)));
typedef float f32x4  __attribute__((ext_vector_type(4)));
typedef __fp16 h16x2 __attribute__((ext_vector_type(2)));

union FU  { bf16x8 v; unsigned u[4]; };
union FU16{ f16x8  v; unsigned u[4]; };

// ---------- helpers ----------
__device__ __forceinline__ void sincos_rev(float rv, float& sn, float& cs){
    sn = __builtin_amdgcn_sinf(rv);   // sin(2*pi*rv)
    cs = __builtin_amdgcn_cosf(rv);
}
__device__ __forceinline__ int rev7(int v){ return (int)(__brev((unsigned)v) >> 25); }

__device__ __forceinline__ unsigned f2bf(float f){
    unsigned u = __float_as_uint(f);
    return (u + 0x7FFFu + ((u >> 16) & 1u)) >> 16;   // round-to-nearest-even
}
__device__ __forceinline__ float bf2f(unsigned h){ return __uint_as_float(h << 16); }
// pack fp32 -> (bf16 hi | bf16 lo) in one u32
__device__ __forceinline__ unsigned packsplit(float v){
    unsigned h = f2bf(v);
    float r = v - bf2f(h);
    unsigned l = f2bf(r);
    return (h << 16) | l;
}

// fp16x2 pack/unpack: packh(a,b) -> (a in LOW 16, b in HIGH 16)
union HU2 { h16x2 h; unsigned u; };
__device__ __forceinline__ unsigned packh(float a, float b){
    HU2 z; z.h = __builtin_amdgcn_cvt_pkrtz(a, b); return z.u;
}
__device__ __forceinline__ void unpackh(unsigned u, float& a, float& b){
    HU2 z; z.u = u; a = (float)z.h.x; b = (float)z.h.y;
}

// ---------- sign/identity-folded per-lane twiddles ----------
struct TwF { float cw[6], sw[6], sg[6], c6, s6; };
__device__ __forceinline__ void make_twf(TwF& t){
    const int l = threadIdx.x & 63;
    #pragma unroll
    for (int lg = 0; lg < 6; ++lg){
        int m = 1 << lg;
        bool up = (l & m) != 0;
        int e = (l & (m-1)) * (64 >> lg);
        float sn, cs; sincos_rev((float)e * 0.0078125f, sn, cs);
        t.cw[lg] = up ? cs : 1.f;
        t.sw[lg] = up ? -sn : 0.f;
        t.sg[lg] = up ? -1.f : 1.f;
    }
    sincos_rev((float)l * 0.0078125f, t.s6, t.c6);
}
struct TwI { float cw[6], sw[6], c6, s6; };
__device__ __forceinline__ void make_twi(TwI& t){
    const int l = threadIdx.x & 63;
    #pragma unroll
    for (int lg = 0; lg < 6; ++lg){
        int m = 1 << lg;
        bool up = (l & m) != 0;
        int e = (l & (m-1)) * (64 >> lg);
        float sn, cs; sincos_rev((float)e * 0.0078125f, sn, cs);
        t.cw[lg] = up ? -cs : cs;
        t.sw[lg] = up ? -sn : sn;
    }
    sincos_rev((float)l * 0.0078125f, t.s6, t.c6);
}

// DIF forward: natural in, slot j holds X[rev7(j)] out. W = e^{-2pi i/128}
__device__ __forceinline__ void dif128t(const TwF& t, float& r0, float& i0, float& r1, float& i1){
    {
        float ar = r0 + r1, ai = i0 + i1;
        float br = r0 - r1, bi = i0 - i1;
        r0 = ar; i0 = ai;
        r1 =  br*t.c6 + bi*t.s6;
        i1 = -br*t.s6 + bi*t.c6;
    }
    #pragma unroll
    for (int lg = 5; lg >= 0; --lg){
        int m = 1 << lg;
        float cw = t.cw[lg], sw = t.sw[lg], sg = t.sg[lg];
        float pr = __shfl_xor(r0, m, 64), pi = __shfl_xor(i0, m, 64);
        float tr = fmaf(sg, r0, pr), ti = fmaf(sg, i0, pi);
        r0 = tr*cw - ti*sw;
        i0 = tr*sw + ti*cw;
        pr = __shfl_xor(r1, m, 64); pi = __shfl_xor(i1, m, 64);
        tr = fmaf(sg, r1, pr); ti = fmaf(sg, i1, pi);
        r1 = tr*cw - ti*sw;
        i1 = tr*sw + ti*cw;
    }
}

// DIT inverse (unnormalized): slot j holds X[rev7(j)] in, natural out. W = e^{+2pi i/128}
__device__ __forceinline__ void dit128t(const TwI& t, float& r0, float& i0, float& r1, float& i1){
    const int l = threadIdx.x & 63;
    #pragma unroll
    for (int lg = 0; lg <= 5; ++lg){
        int m = 1 << lg;
        bool up = (l & m) != 0;
        float cw = t.cw[lg], sw = t.sw[lg];
        float pr = __shfl_xor(r0, m, 64), pi = __shfl_xor(i0, m, 64);
        float vr = up ? r0 : pr, vi = up ? i0 : pi;
        float ar = up ? pr : r0, ai = up ? pi : i0;
        r0 = fmaf(vr, cw, fmaf(vi, -sw, ar));
        i0 = fmaf(vr, sw, fmaf(vi,  cw, ai));
        pr = __shfl_xor(r1, m, 64); pi = __shfl_xor(i1, m, 64);
        vr = up ? r1 : pr; vi = up ? i1 : pi;
        ar = up ? pr : r1; ai = up ? pi : i1;
        r1 = fmaf(vr, cw, fmaf(vi, -sw, ar));
        i1 = fmaf(vr, sw, fmaf(vi,  cw, ai));
    }
    {
        float wr = r1*t.c6 - i1*t.s6, wi = r1*t.s6 + i1*t.c6;
        float ar = r0 + wr, ai = i0 + wi;
        r1 = r0 - wr; i1 = i0 - wi;
        r0 = ar; i0 = ai;
    }
}

// ---------- K1: fused forward fft2 per image -> fp16 half-planes SpecR/SpecI ----------
// Spectrum stored as fp16 pairs: u32 m holds positions (2m, 2m+1) of a plane.
__global__ __launch_bounds__(1024, 8) void k_fft2_fwd(const float* __restrict__ x,
                                                   unsigned* __restrict__ spR, unsigned* __restrict__ spI,
                                                   float* __restrict__ norm2){
    __shared__ unsigned sp[128*129];
    __shared__ float red[16];
    int lane = threadIdx.x & 63, wave = threadIdx.x >> 6;
    int img = blockIdx.x;
    TwF tw; make_twf(tw);
    const float* base = x + (size_t)img * NFFT;
    #pragma unroll 2
    for (int it = 0; it < 8; ++it){
        int h = (wave << 3) + it;
        float a0 = base[h*128 + lane], b0 = 0.f;
        float a1 = base[h*128 + lane + 64], b1 = 0.f;
        dif128t(tw, a0, b0, a1, b1);
        sp[lane*129 + h]      = packh(a0, b0);
        sp[(lane+64)*129 + h] = packh(a1, b1);
    }
    __syncthreads();
    float acc = 0.f;
    #pragma unroll 2
    for (int it = 0; it < 8; ++it){
        int j = (wave << 3) + it;
        float a0, b0, a1, b1;
        unpackh(sp[j*129 + lane],      a0, b0);
        unpackh(sp[j*129 + lane + 64], a1, b1);
        dif128t(tw, a0, b0, a1, b1);
        acc += a0*a0 + b0*b0 + a1*a1 + b1*b1;
        // pack pairs across adjacent lanes: even lane writes re-plane, odd writes im-plane
        float t0 = __shfl_xor(a0, 1, 64), u0 = __shfl_xor(b0, 1, 64);
        float t1 = __shfl_xor(a1, 1, 64), u1 = __shfl_xor(b1, 1, 64);
        size_t m = (size_t)img*8192 + (size_t)j*64;
        int k = lane >> 1;
        if (!(lane & 1)){
            spR[m + k]      = packh(a0, t0);
            spR[m + 32 + k] = packh(a1, t1);
        } else {
            spI[m + k]      = packh(u0, b0);
            spI[m + 32 + k] = packh(u1, b1);
        }
    }
    #pragma unroll
    for (int m = 32; m >= 1; m >>= 1) acc += __shfl_xor(acc, m, 64);
    if (lane == 0) red[wave] = acc;
    __syncthreads();
    if (threadIdx.x == 0){
        float s = 0.f;
        #pragma unroll
        for (int i = 0; i < 16; ++i) s += red[i];
        norm2[img] = s;
    }
}

// ---------- K2: gram via f16 MFMA, zero-conversion staging ----------
// G[bh][c][d] = sum_n X[c][n]*X[d][n] (complex). Gre = Xr Xr^T + (-Xi) Xi^T; Gim = Xr Xi^T + Xi Xr^T.
__global__ __launch_bounds__(256) void k_gram(const unsigned* __restrict__ spR, const unsigned* __restrict__ spI,
                                              float* __restrict__ Gpart){
    __shared__ unsigned lds[2*32*132];
    int t = threadIdx.x, lane = t & 63, wave = t >> 6;
    int bh = blockIdx.x >> 5;
    int ks = blockIdx.x & 31;          // 32 k-splits, K=512 each
    size_t cbase2 = (size_t)bh * 32 * 8192;
    int k0blk = ks << 9;

    int sc = t >> 3, tk = t & 7;

    f32x4 aRe[2][2], aIm[2][2];
    #pragma unroll
    for (int i = 0; i < 2; ++i)
        #pragma unroll
        for (int j = 0; j < 2; ++j){ aRe[i][j] = (f32x4){0,0,0,0}; aIm[i][j] = (f32x4){0,0,0,0}; }

    for (int tile = 0; tile < 2; ++tile){
        int kb = k0blk + (tile << 8);   // 256-wide k tile = 128 u32 per channel
        __syncthreads();
        {
            const unsigned* pr  = spR + cbase2 + (size_t)sc*8192 + (kb >> 1) + tk*16;
            const unsigned* pi_ = spI + cbase2 + (size_t)sc*8192 + (kb >> 1) + tk*16;
            unsigned* dr = &lds[sc*132 + tk*16];
            unsigned* di = &lds[32*132 + sc*132 + tk*16];
            #pragma unroll
            for (int j = 0; j < 4; ++j){
                *(uint4*)(dr + 4*j) = *(const uint4*)(pr + 4*j);
                *(uint4*)(di + 4*j) = *(const uint4*)(pi_ + 4*j);
            }
        }
        __syncthreads();
        #pragma unroll
        for (int ss = 0; ss < 2; ++ss){
            int s = wave + (ss << 2);
            int kbase = (s << 4) + ((lane >> 4) << 2);
            FU16 fr0, fr1, fi0, fi1, fn0, fn1;
            *(uint4*)fr0.u = *(const uint4*)&lds[ (lane & 15)*132 + kbase ];
            *(uint4*)fr1.u = *(const uint4*)&lds[ ((lane & 15) + 16)*132 + kbase ];
            *(uint4*)fi0.u = *(const uint4*)&lds[ 32*132 + (lane & 15)*132 + kbase ];
            *(uint4*)fi1.u = *(const uint4*)&lds[ 32*132 + ((lane & 15) + 16)*132 + kbase ];
            #pragma unroll
            for (int p = 0; p < 4; ++p){ fn0.u[p] = fi0.u[p] ^ 0x80008000u; fn1.u[p] = fi1.u[p] ^ 0x80008000u; }
            aRe[0][0] = __builtin_amdgcn_mfma_f32_16x16x32_f16(fr0.v, fr0.v, aRe[0][0], 0, 0, 0);
            aRe[0][0] = __builtin_amdgcn_mfma_f32_16x16x32_f16(fn0.v, fi0.v, aRe[0][0], 0, 0, 0);
            aRe[0][1] = __builtin_amdgcn_mfma_f32_16x16x32_f16(fr0.v, fr1.v, aRe[0][1], 0, 0, 0);
            aRe[0][1] = __builtin_amdgcn_mfma_f32_16x16x32_f16(fn0.v, fi1.v, aRe[0][1], 0, 0, 0);
            aRe[1][0] = __builtin_amdgcn_mfma_f32_16x16x32_f16(fr1.v, fr0.v, aRe[1][0], 0, 0, 0);
            aRe[1][0] = __builtin_amdgcn_mfma_f32_16x16x32_f16(fn1.v, fi0.v, aRe[1][0], 0, 0, 0);
            aRe[1][1] = __builtin_amdgcn_mfma_f32_16x16x32_f16(fr1.v, fr1.v, aRe[1][1], 0, 0, 0);
            aRe[1][1] = __builtin_amdgcn_mfma_f32_16x16x32_f16(fn1.v, fi1.v, aRe[1][1], 0, 0, 0);
            aIm[0][0] = __builtin_amdgcn_mfma_f32_16x16x32_f16(fr0.v, fi0.v, aIm[0][0], 0, 0, 0);
            aIm[0][0] = __builtin_amdgcn_mfma_f32_16x16x32_f16(fi0.v, fr0.v, aIm[0][0], 0, 0, 0);
            aIm[0][1] = __builtin_amdgcn_mfma_f32_16x16x32_f16(fr0.v, fi1.v, aIm[0][1], 0, 0, 0);
            aIm[0][1] = __builtin_amdgcn_mfma_f32_16x16x32_f16(fi0.v, fr1.v, aIm[0][1], 0, 0, 0);
            aIm[1][0] = __builtin_amdgcn_mfma_f32_16x16x32_f16(fr1.v, fi0.v, aIm[1][0], 0, 0, 0);
            aIm[1][0] = __builtin_amdgcn_mfma_f32_16x16x32_f16(fi1.v, fr0.v, aIm[1][0], 0, 0, 0);
            aIm[1][1] = __builtin_amdgcn_mfma_f32_16x16x32_f16(fr1.v, fi1.v, aIm[1][1], 0, 0, 0);
            aIm[1][1] = __builtin_amdgcn_mfma_f32_16x16x32_f16(fi1.v, fr1.v, aIm[1][1], 0, 0, 0);
        }
    }
    __syncthreads();
    float* rbuf = (float*)lds;
    int dcol = lane & 15, rrow = lane >> 4;
    #pragma unroll
    for (int i = 0; i < 2; ++i)
        #pragma unroll
        for (int j = 0; j < 2; ++j)
            #pragma unroll
            for (int r = 0; r < 4; ++r){
                int c = (i << 4) + (rrow << 2) + r;
                int d = (j << 4) + dcol;
                rbuf[wave*2048 + ((c << 5) + d)*2    ] = aRe[i][j][r];
                rbuf[wave*2048 + ((c << 5) + d)*2 + 1] = aIm[i][j][r];
            }
    __syncthreads();
    float* gp = Gpart + (size_t)blockIdx.x * 2048;
    for (int idx = t; idx < 2048; idx += 256)
        gp[idx] = rbuf[idx] + rbuf[2048 + idx] + rbuf[4096 + idx] + rbuf[6144 + idx];
}

// ---------- K2b: reduce 32 k-split partials per bh ----------
__global__ __launch_bounds__(256) void k_gram_red(const float* __restrict__ Gpart, float* __restrict__ G){
    int bh = blockIdx.x >> 3;
    int q  = ((blockIdx.x & 7) << 8) + threadIdx.x;
    const float* gp = Gpart + (size_t)bh * 32 * 2048 + q;
    float s = 0.f;
    #pragma unroll 8
    for (int p = 0; p < 32; ++p) s += gp[(size_t)p * 2048];
    G[(size_t)bh * 2048 + q] = s;
}

// ---------- K3: normalize, temperature, complex softmax, fold IF32 * (1/524288) ----------
__global__ __launch_bounds__(256) void k_attn(const float* __restrict__ G, const float* __restrict__ norm2,
                                              const float* __restrict__ temp, float* __restrict__ attn2){
    __shared__ float ar[32*33], ai[32*33];
    int bh = blockIdx.x, h = bh & 7, t = threadIdx.x;
    if (t < 32){
        float tv = temp[h];
        float nc = fmaxf(sqrtf(norm2[(bh<<5) + t]), 1e-12f);
        const float* gr = G + (size_t)bh*2048 + t*64;
        float mr = -1e30f, mi = -1e30f;
        for (int d = 0; d < 32; ++d){
            float nd = fmaxf(sqrtf(norm2[(bh<<5) + d]), 1e-12f);
            float s = tv / (nc * nd);
            float vr = gr[d*2] * s, vi = gr[d*2+1] * s;
            ar[t*33+d] = vr; ai[t*33+d] = vi;
            mr = fmaxf(mr, vr); mi = fmaxf(mi, vi);
        }
        float sr = 0.f, si = 0.f;
        for (int d = 0; d < 32; ++d){
            float er = __expf(ar[t*33+d] - mr), ei = __expf(ai[t*33+d] - mi);
            ar[t*33+d] = er; ai[t*33+d] = ei; sr += er; si += ei;
        }
        sr = 1.f/sr; si = 1.f/si;
        for (int d = 0; d < 32; ++d){ ar[t*33+d] *= sr; ai[t*33+d] *= si; }
    }
    __syncthreads();
    const float S = 1.f / 524288.f;
    for (int q = t; q < 1024; q += 256){
        int e = q >> 5, d = q & 31;
        float sr = 0.f, si = 0.f;
        for (int c = 0; c < 32; ++c){
            float sn, cs; sincos_rev((float)((e*c) & 31) * 0.03125f, sn, cs);
            float xr = ar[c*33+d], xi = ai[c*33+d];
            sr += cs*xr - sn*xi;
            si += cs*xi + sn*xr;
        }
        attn2[(size_t)bh*2048 + q*2]     = sr * S;
        attn2[(size_t)bh*2048 + q*2 + 1] = si * S;
    }
}

// ---------- K4: mix[e][n] = sum_d attn2[e][d] * X[d][n] via f16 MFMA ----------
// Output: fp16-packed complex (re|im per u32, element-indexed) for k_ifft_n.
__global__ __launch_bounds__(256) void k_mix(const unsigned* __restrict__ spR, const unsigned* __restrict__ spI,
                                             const float* __restrict__ attn2,
                                             unsigned* __restrict__ om){
    __shared__ unsigned lds[2*32*36];   // [plane][d][u32 col 0..31 + pad]
    __shared__ float a2s[2048];
    int t = threadIdx.x, lane = t & 63, wave = t >> 6;
    int quad = lane >> 4, l15 = lane & 15;
    int bh = blockIdx.x >> 5;
    int n0 = (blockIdx.x & 31) << 9;
    size_t cbase2 = (size_t)bh * 32 * 8192;
    {
        const float4* s4 = (const float4*)(attn2 + (size_t)bh*2048);
        float4* d4 = (float4*)a2s;
        d4[t] = s4[t]; d4[t + 256] = s4[t + 256];
    }
    __syncthreads();
    FU16 Ar[2], Ai[2];
    #pragma unroll
    for (int et = 0; et < 2; ++et){
        int e = (et << 4) + l15;
        #pragma unroll
        for (int p = 0; p < 4; ++p){
            int d0 = (quad << 3) + (p << 1);
            Ar[et].u[p] = packh(a2s[(e*32 + d0)*2],     a2s[(e*32 + d0 + 1)*2]);
            Ai[et].u[p] = packh(a2s[(e*32 + d0)*2 + 1], a2s[(e*32 + d0 + 1)*2 + 1]);
        }
    }
    int sd = t >> 3, sc4 = (t & 7) << 2;
    for (int tile = 0; tile < 8; ++tile){
        int nb = n0 + (tile << 6);
        __syncthreads();
        {
            size_t g2 = cbase2 + (size_t)sd*8192 + (nb >> 1) + sc4;
            *(uint4*)&lds[sd*36 + sc4]         = *(const uint4*)&spR[g2];
            *(uint4*)&lds[32*36 + sd*36 + sc4] = *(const uint4*)&spI[g2];
        }
        __syncthreads();
        int colb = (wave << 4) + l15;
        int cb2 = colb >> 1; bool codd = colb & 1;
        FU16 Xr, Xi, Xn;
        #pragma unroll
        for (int p = 0; p < 4; ++p){
            int d0 = (quad << 3) + (p << 1);
            unsigned e0 = lds[d0*36 + cb2], e1 = lds[(d0+1)*36 + cb2];
            Xr.u[p] = codd ? ((e0 >> 16) | (e1 & 0xFFFF0000u)) : ((e0 & 0xFFFFu) | (e1 << 16));
            e0 = lds[32*36 + d0*36 + cb2]; e1 = lds[32*36 + (d0+1)*36 + cb2];
            Xi.u[p] = codd ? ((e0 >> 16) | (e1 & 0xFFFF0000u)) : ((e0 & 0xFFFFu) | (e1 << 16));
            Xn.u[p] = Xi.u[p] ^ 0x80008000u;
        }
        #pragma unroll
        for (int et = 0; et < 2; ++et){
            f32x4 ar = (f32x4){0,0,0,0}, ai = (f32x4){0,0,0,0};
            ar = __builtin_amdgcn_mfma_f32_16x16x32_f16(Ar[et].v, Xr.v, ar, 0, 0, 0);
            ar = __builtin_amdgcn_mfma_f32_16x16x32_f16(Ai[et].v, Xn.v, ar, 0, 0, 0);
            ai = __builtin_amdgcn_mfma_f32_16x16x32_f16(Ar[et].v, Xi.v, ai, 0, 0, 0);
            ai = __builtin_amdgcn_mfma_f32_16x16x32_f16(Ai[et].v, Xr.v, ai, 0, 0, 0);
            #pragma unroll
            for (int r = 0; r < 4; ++r){
                int e = (et << 4) + (quad << 2) + r;
                om[cbase2*2 + (size_t)e*NFFT + nb + colb] = packh(ar[r], ai[r]);
            }
        }
    }
}

// ---------- K5: fused 16384-pt inverse FFT + abs per row; fp16-packed complex in, bf16(hi|lo) out ----------
__global__ __launch_bounds__(1024, 8) void k_ifft_n(unsigned* io){
    __shared__ unsigned sp[128*129];
    int lane = threadIdx.x & 63, wave = threadIdx.x >> 6;
    size_t rb = (size_t)blockIdx.x * NFFT;
    TwI tw; make_twi(tw);
    #pragma unroll 2
    for (int it = 0; it < 8; ++it){
        int jw = (wave << 3) + it;
        size_t base = rb + ((size_t)jw << 7);
        float a0, b0, a1, b1;
        unpackh(io[base + lane], a0, b0);
        unpackh(io[base + lane + 64], a1, b1);
        dit128t(tw, a0, b0, a1, b1);
        int kw = rev7(jw);
        float sn, cs;
        sincos_rev((float)(lane * kw) * 6.103515625e-05f, sn, cs);
        float r = a0*cs - b0*sn, i2 = a0*sn + b0*cs;
        sp[lane*129 + jw] = packh(r, i2);
        sincos_rev((float)((lane + 64) * kw) * 6.103515625e-05f, sn, cs);
        r = a1*cs - b1*sn; i2 = a1*sn + b1*cs;
        sp[(lane+64)*129 + jw] = packh(r, i2);
    }
    __syncthreads();
    unsigned av[8][2];
    #pragma unroll 2
    for (int it = 0; it < 8; ++it){
        int pw = (wave << 3) + it;
        float a0, b0, a1, b1;
        unpackh(sp[pw*129 + lane],      a0, b0);
        unpackh(sp[pw*129 + lane + 64], a1, b1);
        dit128t(tw, a0, b0, a1, b1);
        av[it][0] = packsplit(sqrtf(a0*a0 + b0*b0));
        av[it][1] = packsplit(sqrtf(a1*a1 + b1*b1));
    }
    __syncthreads();
    #pragma unroll 2
    for (int it = 0; it < 8; ++it){
        int pw = (wave << 3) + it;
        sp[lane*129 + pw] = av[it][0];
        sp[(lane+64)*129 + pw] = av[it][1];
    }
    __syncthreads();
    int row = threadIdx.x >> 3, cb = (threadIdx.x & 7) << 4;
    size_t ob = rb + ((size_t)row << 7) + cb;
    const unsigned* s = &sp[row*129 + cb];
    #pragma unroll
    for (int q = 0; q < 4; ++q)
        *(uint4*)(io + ob + (q << 2)) = make_uint4(s[q*4], s[q*4+1], s[q*4+2], s[q*4+3]);
}

// ---------- K6: gating, IN-PLACE on fp16 half-planes ----------
__global__ __launch_bounds__(256) void k_gate(unsigned* spR, unsigned* spI,
                                              const float* __restrict__ w1, const float* __restrict__ b1,
                                              const float* __restrict__ bg, const float* __restrict__ bb_,
                                              const float* __restrict__ bm, const float* __restrict__ bv,
                                              const float* __restrict__ w2, const float* __restrict__ b2){
    __shared__ float w1T[256*17];
    __shared__ float w2s[256*16];
    __shared__ float yred[256*17];
    int t = threadIdx.x, g = t >> 6, col = t & 63;
    #pragma unroll
    for (int i = 0; i < 16; ++i) w1T[t*17 + i] = w1[i*256 + t];
    {
        const float4* s4 = (const float4*)w2; float4* d4 = (float4*)w2s;
        #pragma unroll
        for (int i = 0; i < 4; ++i) d4[i*256 + t] = s4[i*256 + t];
    }
    __syncthreads();
    int b = blockIdx.x >> 8;
    int n = ((blockIdx.x & 255) << 6) + col;
    int odd = n & 1;
    size_t base2 = (((size_t)b << 8) << 13) + (n >> 1);
    float y[16];
    #pragma unroll
    for (int r = 0; r < 16; ++r) y[r] = 0.f;
    for (int c = g << 6; c < (g << 6) + 64; ++c){
        float lo, hi; unpackh(spR[base2 + ((size_t)c << 13)], lo, hi);
        float xr = odd ? hi : lo;
        #pragma unroll
        for (int r = 0; r < 16; ++r) y[r] += w1T[c*17 + r] * xr;
    }
    #pragma unroll
    for (int r = 0; r < 16; ++r) yred[t*17 + r] = y[r];
    __syncthreads();
    #pragma unroll
    for (int r = 0; r < 16; ++r){
        float v = yred[col*17 + r] + yred[(col+64)*17 + r]
                + yred[(col+128)*17 + r] + yred[(col+192)*17 + r] + b1[r];
        v = (v - bm[r]) * rsqrtf(bv[r] + 1e-5f) * bg[r] + bb_[r];
        y[r] = fmaxf(v, 0.f);
    }
    for (int o = g << 6; o < (g << 6) + 64; ++o){
        float s = b2[o];
        #pragma unroll
        for (int r = 0; r < 16; ++r) s += w2s[o*16 + r] * y[r];
        float gg = 1.f / (1.f + __expf(-s)) * 6.103515625e-05f;   // sigmoid * 1/16384
        float ggN = __shfl_xor(gg, 1, 64);
        size_t mi = base2 + ((size_t)o << 13);
        if (!odd){   // even col updates re-plane u32 (pair n, n+1)
            float lo, hi; unpackh(spR[mi], lo, hi);
            spR[mi] = packh(gg*lo, ggN*hi);
        } else {     // odd col updates im-plane u32
            float lo, hi; unpackh(spI[mi], lo, hi);
            spI[mi] = packh(ggN*lo, gg*hi);
        }
    }
}

// ---------- K7: fused ifft2 per image + abs -> PACKED bf16(hi|lo) into Cat1 ----------
__global__ __launch_bounds__(1024, 8) void k_ifft2_gate(const unsigned* __restrict__ spR,
                                                        const unsigned* __restrict__ spI,
                                                        unsigned* __restrict__ outp){
    __shared__ unsigned sp[128*129];
    int lane = threadIdx.x & 63, wave = threadIdx.x >> 6;
    size_t ib = (size_t)blockIdx.x * NFFT;
    TwI tw; make_twi(tw);
    #pragma unroll 2
    for (int it = 0; it < 8; ++it){
        int jw = (wave << 3) + it;
        size_t m = (ib + ((size_t)jw << 7)) >> 1;
        int k = lane >> 1; bool od = lane & 1;
        float lo, hi, a0, b0, a1, b1;
        unpackh(spR[m + k], lo, hi);      a0 = od ? hi : lo;
        unpackh(spI[m + k], lo, hi);      b0 = od ? hi : lo;
        unpackh(spR[m + 32 + k], lo, hi); a1 = od ? hi : lo;
        unpackh(spI[m + 32 + k], lo, hi); b1 = od ? hi : lo;
        dit128t(tw, a0, b0, a1, b1);
        sp[lane*129 + jw]      = packh(a0, b0);
        sp[(lane+64)*129 + jw] = packh(a1, b1);
    }
    __syncthreads();
    #pragma unroll 2
    for (int it = 0; it < 8; ++it){
        int ph = (wave << 3) + it;
        float a0, b0, a1, b1;
        unpackh(sp[ph*129 + lane],      a0, b0);
        unpackh(sp[ph*129 + lane + 64], a1, b1);
        dit128t(tw, a0, b0, a1, b1);
        size_t o = ib + ((size_t)ph << 7);
        outp[o + lane]      = packsplit(sqrtf(a0*a0 + b0*b0));
        outp[o + lane + 64] = packsplit(sqrtf(a1*a1 + b1*b1));
    }
}

// ---------- K7b: pack pw into (hi|lo) u32 ----------
__global__ __launch_bounds__(256) void k_pw_cvt(const float* __restrict__ pw, unsigned* __restrict__ pwp){
    int i = (blockIdx.x << 10) + (threadIdx.x << 2);
    float4 v = *(const float4*)(pw + i);
    uint4 o;
    o.x = packsplit(v.x); o.y = packsplit(v.y); o.z = packsplit(v.z); o.w = packsplit(v.w);
    *(uint4*)(pwp + i) = o;
}

// ---------- K8: projection via bf16 MFMA, pre-packed inputs ----------
__global__ __launch_bounds__(256) void k_proj(const unsigned* __restrict__ cat0, const unsigned* __restrict__ cat1,
                                              const unsigned* __restrict__ pwp, float* __restrict__ out){
    __shared__ unsigned As[128*33];
    __shared__ unsigned Bs[32*129];
    int t = threadIdx.x, lane = t & 63, wave = t >> 6;
    int quad = lane >> 4, l15 = lane & 15;
    int b  = blockIdx.x >> 8;
    int mo = (blockIdx.x >> 7) & 1;
    int nt = blockIdx.x & 127;
    int n0 = nt << 7;
    int wr = (wave >> 1) << 6;
    int wc = (wave & 1) << 6;

    f32x4 acc[4][4];
    #pragma unroll
    for (int i = 0; i < 4; ++i)
        #pragma unroll
        for (int j = 0; j < 4; ++j) acc[i][j] = (f32x4){0.f,0.f,0.f,0.f};

    int ao = t >> 1, ak = (t & 1) << 4;
    int bk = t >> 5, bn = t & 31;

    for (int ks = 0; ks < 16; ++ks){
        int k0 = ks << 5;
        __syncthreads();
        {
            const unsigned* ap = pwp + (size_t)((mo << 7) + ao)*512 + k0 + ak;
            #pragma unroll
            for (int i = 0; i < 16; ++i) As[ao*33 + ak + i] = ap[i];
        }
        {
            #pragma unroll
            for (int p = 0; p < 4; ++p){
                int q = k0 + (p << 3) + bk;
                const unsigned* srow = (q < 256) ? (cat0 + (size_t)((b<<8) + q) * NFFT)
                                                 : (cat1 + (size_t)((b<<8) + (q-256)) * NFFT);
                #pragma unroll
                for (int i = 0; i < 4; ++i){
                    int n = bn + (i << 5);
                    Bs[((p<<3) + bk)*129 + n] = srow[n0 + n];
                }
            }
        }
        __syncthreads();
        FU Ah[4], Al[4], Bh[4], Bl[4];
        #pragma unroll
        for (int mi = 0; mi < 4; ++mi){
            const unsigned* ap = &As[(wr + (mi << 4) + l15)*33 + (quad << 3)];
            #pragma unroll
            for (int p = 0; p < 4; ++p){
                unsigned e0 = ap[2*p], e1 = ap[2*p+1];
                Ah[mi].u[p] = (e0 >> 16) | (e1 & 0xFFFF0000u);
                Al[mi].u[p] = (e0 & 0xFFFFu) | (e1 << 16);
            }
        }
        #pragma unroll
        for (int ni = 0; ni < 4; ++ni){
            int n = wc + (ni << 4) + l15;
            #pragma unroll
            for (int p = 0; p < 4; ++p){
                unsigned e0 = Bs[((quad << 3) + 2*p)*129 + n];
                unsigned e1 = Bs[((quad << 3) + 2*p + 1)*129 + n];
                Bh[ni].u[p] = (e0 >> 16) | (e1 & 0xFFFF0000u);
                Bl[ni].u[p] = (e0 & 0xFFFFu) | (e1 << 16);
            }
        }
        #pragma unroll
        for (int mi = 0; mi < 4; ++mi)
            #pragma unroll
            for (int ni = 0; ni < 4; ++ni){
                acc[mi][ni] = __builtin_amdgcn_mfma_f32_16x16x32_bf16(Ah[mi].v, Bh[ni].v, acc[mi][ni], 0, 0, 0);
                acc[mi][ni] = __builtin_amdgcn_mfma_f32_16x16x32_bf16(Ah[mi].v, Bl[ni].v, acc[mi][ni], 0, 0, 0);
                acc[mi][ni] = __builtin_amdgcn_mfma_f32_16x16x32_bf16(Al[mi].v, Bh[ni].v, acc[mi][ni], 0, 0, 0);
            }
    }
    size_t obase = (size_t)((b << 8) + (mo << 7));
    #pragma unroll
    for (int mi = 0; mi < 4; ++mi)
        #pragma unroll
        for (int ni = 0; ni < 4; ++ni){
            int o_ = wr + (mi << 4) + (quad << 2);
            int n_ = n0 + wc + (ni << 4) + l15;
            float* op = out + (obase + o_)*NFFT + n_;
            #pragma unroll
            for (int r = 0; r < 4; ++r) op[(size_t)r*NFFT] = acc[mi][ni][r];
        }
}

// ---------- host ----------
extern "C" void kernel_launch(void* const* d_in, const int* in_sizes, int n_in,
                              void* d_out, int out_size, void* d_ws, size_t ws_size,
                              hipStream_t stream) {
    const float* x    = (const float*)d_in[0];
    const float* temp = (const float*)d_in[1];
    const float* w1   = (const float*)d_in[2];
    const float* b1   = (const float*)d_in[3];
    const float* bg   = (const float*)d_in[4];
    const float* bb_  = (const float*)d_in[5];
    const float* bm   = (const float*)d_in[6];
    const float* bv   = (const float*)d_in[7];
    const float* w2   = (const float*)d_in[8];
    const float* b2   = (const float*)d_in[9];
    const float* pw   = (const float*)d_in[10];
    float* out = (float*)d_out;

    float* ws = (float*)d_ws;
    unsigned* SpecR = (unsigned*)ws;             // fp16 re half-plane, NP/2 u32
    unsigned* SpecI = SpecR + (NP >> 1);         // fp16 im half-plane
    unsigned* Ecat  = (unsigned*)(ws + NP);      // mix out (fp16 cplx) -> ifft_n in-place (bf16 split) -> cat0
    unsigned* Cat1  = (unsigned*)(ws + 2*NP);    // ifft2_gate out (bf16 split) -> cat1
    float* norm2 = ws + 3*NP;                    // 1024
    float* G     = norm2 + 1024;                 // 65536
    float* attn2 = G + 65536;                    // 65536
    unsigned* pwpack = (unsigned*)(attn2 + 65536);  // 131072
    float* Gpart = (float*)Ecat;                 // 8 MB scratch, dead until k_mix

    size_t need = (3*NP + 1024 + 65536 + 65536 + 131072) * sizeof(float);
    if (ws_size < need) return;

    k_pw_cvt<<<128, 256, 0, stream>>>(pw, pwpack);
    k_fft2_fwd<<<1024, 1024, 0, stream>>>(x, SpecR, SpecI, norm2);
    k_gram<<<1024, 256, 0, stream>>>(SpecR, SpecI, Gpart);
    k_gram_red<<<256, 256, 0, stream>>>(Gpart, G);
    k_attn<<<32, 256, 0, stream>>>(G, norm2, temp, attn2);
    k_mix<<<1024, 256, 0, stream>>>(SpecR, SpecI, attn2, Ecat);
    k_ifft_n<<<1024, 1024, 0, stream>>>(Ecat);
    k_gate<<<1024, 256, 0, stream>>>(SpecR, SpecI, w1, b1, bg, bb_, bm, bv, w2, b2);
    k_ifft2_gate<<<1024, 1024, 0, stream>>>(SpecR, SpecI, Cat1);
    k_proj<<<1024, 256, 0, stream>>>(Ecat, Cat1, pwpack, out);
    (void)in_sizes; (void)n_in; (void)out_size; (void)ws_size;
}

// Round 7
// 479.648 us; speedup vs baseline: 1.5454x; 1.0812x over previous
//
#include <hip/hip_runtime.h>
#include <math.h>

// Problem constants: b=4, c=256, heads=8, c/head=32, h=w=128, n=16384, cr=16
#define NFFT 16384
static constexpr size_t NP = 16777216; // one fp32 plane = 1024 * 16384 floats

typedef short bf16x8 __attribute__((ext_vector_type(8)));
typedef __fp16 f16x8 __attribute__((ext_vector_type(8)));
typedef float f32x4  __attribute__((ext_vector_type(4)));
typedef __fp16 h16x2 __attribute__((ext_vector_type(2)));

union FU  { bf16x8 v; unsigned u[4]; };
union FU16{ f16x8  v; unsigned u[4]; };

// ---------- helpers ----------
__device__ __forceinline__ void sincos_rev(float rv, float& sn, float& cs){
    sn = __builtin_amdgcn_sinf(rv);   // sin(2*pi*rv)
    cs = __builtin_amdgcn_cosf(rv);
}
__device__ __forceinline__ int rev7(int v){ return (int)(__brev((unsigned)v) >> 25); }

__device__ __forceinline__ unsigned f2bf(float f){
    unsigned u = __float_as_uint(f);
    return (u + 0x7FFFu + ((u >> 16) & 1u)) >> 16;   // round-to-nearest-even
}
__device__ __forceinline__ float bf2f(unsigned h){ return __uint_as_float(h << 16); }

// fp16x2 pack/unpack: packh(a,b) -> (a in LOW 16, b in HIGH 16)
union HU2 { h16x2 h; unsigned u; };
__device__ __forceinline__ unsigned packh(float a, float b){
    HU2 z; z.h = __builtin_amdgcn_cvt_pkrtz(a, b); return z.u;
}
__device__ __forceinline__ void unpackh(unsigned u, float& a, float& b){
    HU2 z; z.u = u; a = (float)z.h.x; b = (float)z.h.y;
}

// ---------- sign/identity-folded per-lane twiddles ----------
struct TwF { float cw[6], sw[6], sg[6], c6, s6; };
__device__ __forceinline__ void make_twf(TwF& t){
    const int l = threadIdx.x & 63;
    #pragma unroll
    for (int lg = 0; lg < 6; ++lg){
        int m = 1 << lg;
        bool up = (l & m) != 0;
        int e = (l & (m-1)) * (64 >> lg);
        float sn, cs; sincos_rev((float)e * 0.0078125f, sn, cs);
        t.cw[lg] = up ? cs : 1.f;
        t.sw[lg] = up ? -sn : 0.f;
        t.sg[lg] = up ? -1.f : 1.f;
    }
    sincos_rev((float)l * 0.0078125f, t.s6, t.c6);
}
// DIT (inverse), select-free: every lane multiplies SELF by folded w
// (up lane: w = e^{+2pi i e/128}, down lane: 1), shuffles the product, then
// y = shfl(q) + sg*q  (down sg=+1: x_d + w*x_u; up sg=-1: x_d - w*x_u).
struct TwI { float cw[6], sw[6], sg[6], c6, s6; };
__device__ __forceinline__ void make_twi(TwI& t){
    const int l = threadIdx.x & 63;
    #pragma unroll
    for (int lg = 0; lg < 6; ++lg){
        int m = 1 << lg;
        bool up = (l & m) != 0;
        int e = (l & (m-1)) * (64 >> lg);
        float sn, cs; sincos_rev((float)e * 0.0078125f, sn, cs);
        t.cw[lg] = up ? cs : 1.f;
        t.sw[lg] = up ? sn : 0.f;
        t.sg[lg] = up ? -1.f : 1.f;
    }
    sincos_rev((float)l * 0.0078125f, t.s6, t.c6);
}

// DIF forward: natural in, slot j holds X[rev7(j)] out. W = e^{-2pi i/128}
__device__ __forceinline__ void dif128t(const TwF& t, float& r0, float& i0, float& r1, float& i1){
    {
        float ar = r0 + r1, ai = i0 + i1;
        float br = r0 - r1, bi = i0 - i1;
        r0 = ar; i0 = ai;
        r1 =  br*t.c6 + bi*t.s6;
        i1 = -br*t.s6 + bi*t.c6;
    }
    #pragma unroll
    for (int lg = 5; lg >= 0; --lg){
        int m = 1 << lg;
        float cw = t.cw[lg], sw = t.sw[lg], sg = t.sg[lg];
        float pr = __shfl_xor(r0, m, 64), pi = __shfl_xor(i0, m, 64);
        float tr = fmaf(sg, r0, pr), ti = fmaf(sg, i0, pi);
        r0 = tr*cw - ti*sw;
        i0 = tr*sw + ti*cw;
        pr = __shfl_xor(r1, m, 64); pi = __shfl_xor(i1, m, 64);
        tr = fmaf(sg, r1, pr); ti = fmaf(sg, i1, pi);
        r1 = tr*cw - ti*sw;
        i1 = tr*sw + ti*cw;
    }
}

// DIT inverse (unnormalized): slot j holds X[rev7(j)] in, natural out. W = e^{+2pi i/128}
__device__ __forceinline__ void dit128t(const TwI& t, float& r0, float& i0, float& r1, float& i1){
    #pragma unroll
    for (int lg = 0; lg <= 5; ++lg){
        int m = 1 << lg;
        float cw = t.cw[lg], sw = t.sw[lg], sg = t.sg[lg];
        float qr = r0*cw - i0*sw, qi = r0*sw + i0*cw;
        float pr = __shfl_xor(qr, m, 64), pi = __shfl_xor(qi, m, 64);
        r0 = fmaf(sg, qr, pr);
        i0 = fmaf(sg, qi, pi);
        qr = r1*cw - i1*sw; qi = r1*sw + i1*cw;
        pr = __shfl_xor(qr, m, 64); pi = __shfl_xor(qi, m, 64);
        r1 = fmaf(sg, qr, pr);
        i1 = fmaf(sg, qi, pi);
    }
    {
        float wr = r1*t.c6 - i1*t.s6, wi = r1*t.s6 + i1*t.c6;
        float ar = r0 + wr, ai = i0 + wi;
        r1 = r0 - wr; i1 = i0 - wi;
        r0 = ar; i0 = ai;
    }
}

// ---------- K1: fused forward fft2 per image -> fp16 half-planes SpecR/SpecI ----------
__global__ __launch_bounds__(1024, 8) void k_fft2_fwd(const float* __restrict__ x,
                                                   unsigned* __restrict__ spR, unsigned* __restrict__ spI,
                                                   float* __restrict__ norm2){
    __shared__ unsigned sp[128*129];
    __shared__ float red[16];
    int lane = threadIdx.x & 63, wave = threadIdx.x >> 6;
    int img = blockIdx.x;
    TwF tw; make_twf(tw);
    const float* base = x + (size_t)img * NFFT;
    #pragma unroll 2
    for (int it = 0; it < 8; ++it){
        int h = (wave << 3) + it;
        float a0 = base[h*128 + lane], b0 = 0.f;
        float a1 = base[h*128 + lane + 64], b1 = 0.f;
        dif128t(tw, a0, b0, a1, b1);
        sp[lane*129 + h]      = packh(a0, b0);
        sp[(lane+64)*129 + h] = packh(a1, b1);
    }
    __syncthreads();
    float acc = 0.f;
    #pragma unroll 2
    for (int it = 0; it < 8; ++it){
        int j = (wave << 3) + it;
        float a0, b0, a1, b1;
        unpackh(sp[j*129 + lane],      a0, b0);
        unpackh(sp[j*129 + lane + 64], a1, b1);
        dif128t(tw, a0, b0, a1, b1);
        acc += a0*a0 + b0*b0 + a1*a1 + b1*b1;
        float t0 = __shfl_xor(a0, 1, 64), u0 = __shfl_xor(b0, 1, 64);
        float t1 = __shfl_xor(a1, 1, 64), u1 = __shfl_xor(b1, 1, 64);
        size_t m = (size_t)img*8192 + (size_t)j*64;
        int k = lane >> 1;
        if (!(lane & 1)){
            spR[m + k]      = packh(a0, t0);
            spR[m + 32 + k] = packh(a1, t1);
        } else {
            spI[m + k]      = packh(u0, b0);
            spI[m + 32 + k] = packh(u1, b1);
        }
    }
    #pragma unroll
    for (int m = 32; m >= 1; m >>= 1) acc += __shfl_xor(acc, m, 64);
    if (lane == 0) red[wave] = acc;
    __syncthreads();
    if (threadIdx.x == 0){
        float s = 0.f;
        #pragma unroll
        for (int i = 0; i < 16; ++i) s += red[i];
        norm2[img] = s;
    }
}

// ---------- K2: gram via f16 MFMA, zero-conversion staging ----------
__global__ __launch_bounds__(256) void k_gram(const unsigned* __restrict__ spR, const unsigned* __restrict__ spI,
                                              float* __restrict__ Gpart){
    __shared__ unsigned lds[2*32*132];
    int t = threadIdx.x, lane = t & 63, wave = t >> 6;
    int bh = blockIdx.x >> 5;
    int ks = blockIdx.x & 31;          // 32 k-splits, K=512 each
    size_t cbase2 = (size_t)bh * 32 * 8192;
    int k0blk = ks << 9;

    int sc = t >> 3, tk = t & 7;

    f32x4 aRe[2][2], aIm[2][2];
    #pragma unroll
    for (int i = 0; i < 2; ++i)
        #pragma unroll
        for (int j = 0; j < 2; ++j){ aRe[i][j] = (f32x4){0,0,0,0}; aIm[i][j] = (f32x4){0,0,0,0}; }

    for (int tile = 0; tile < 2; ++tile){
        int kb = k0blk + (tile << 8);
        __syncthreads();
        {
            const unsigned* pr  = spR + cbase2 + (size_t)sc*8192 + (kb >> 1) + tk*16;
            const unsigned* pi_ = spI + cbase2 + (size_t)sc*8192 + (kb >> 1) + tk*16;
            unsigned* dr = &lds[sc*132 + tk*16];
            unsigned* di = &lds[32*132 + sc*132 + tk*16];
            #pragma unroll
            for (int j = 0; j < 4; ++j){
                *(uint4*)(dr + 4*j) = *(const uint4*)(pr + 4*j);
                *(uint4*)(di + 4*j) = *(const uint4*)(pi_ + 4*j);
            }
        }
        __syncthreads();
        #pragma unroll
        for (int ss = 0; ss < 2; ++ss){
            int s = wave + (ss << 2);
            int kbase = (s << 4) + ((lane >> 4) << 2);
            FU16 fr0, fr1, fi0, fi1, fn0, fn1;
            *(uint4*)fr0.u = *(const uint4*)&lds[ (lane & 15)*132 + kbase ];
            *(uint4*)fr1.u = *(const uint4*)&lds[ ((lane & 15) + 16)*132 + kbase ];
            *(uint4*)fi0.u = *(const uint4*)&lds[ 32*132 + (lane & 15)*132 + kbase ];
            *(uint4*)fi1.u = *(const uint4*)&lds[ 32*132 + ((lane & 15) + 16)*132 + kbase ];
            #pragma unroll
            for (int p = 0; p < 4; ++p){ fn0.u[p] = fi0.u[p] ^ 0x80008000u; fn1.u[p] = fi1.u[p] ^ 0x80008000u; }
            aRe[0][0] = __builtin_amdgcn_mfma_f32_16x16x32_f16(fr0.v, fr0.v, aRe[0][0], 0, 0, 0);
            aRe[0][0] = __builtin_amdgcn_mfma_f32_16x16x32_f16(fn0.v, fi0.v, aRe[0][0], 0, 0, 0);
            aRe[0][1] = __builtin_amdgcn_mfma_f32_16x16x32_f16(fr0.v, fr1.v, aRe[0][1], 0, 0, 0);
            aRe[0][1] = __builtin_amdgcn_mfma_f32_16x16x32_f16(fn0.v, fi1.v, aRe[0][1], 0, 0, 0);
            aRe[1][0] = __builtin_amdgcn_mfma_f32_16x16x32_f16(fr1.v, fr0.v, aRe[1][0], 0, 0, 0);
            aRe[1][0] = __builtin_amdgcn_mfma_f32_16x16x32_f16(fn1.v, fi0.v, aRe[1][0], 0, 0, 0);
            aRe[1][1] = __builtin_amdgcn_mfma_f32_16x16x32_f16(fr1.v, fr1.v, aRe[1][1], 0, 0, 0);
            aRe[1][1] = __builtin_amdgcn_mfma_f32_16x16x32_f16(fn1.v, fi1.v, aRe[1][1], 0, 0, 0);
            aIm[0][0] = __builtin_amdgcn_mfma_f32_16x16x32_f16(fr0.v, fi0.v, aIm[0][0], 0, 0, 0);
            aIm[0][0] = __builtin_amdgcn_mfma_f32_16x16x32_f16(fi0.v, fr0.v, aIm[0][0], 0, 0, 0);
            aIm[0][1] = __builtin_amdgcn_mfma_f32_16x16x32_f16(fr0.v, fi1.v, aIm[0][1], 0, 0, 0);
            aIm[0][1] = __builtin_amdgcn_mfma_f32_16x16x32_f16(fi0.v, fr1.v, aIm[0][1], 0, 0, 0);
            aIm[1][0] = __builtin_amdgcn_mfma_f32_16x16x32_f16(fr1.v, fi0.v, aIm[1][0], 0, 0, 0);
            aIm[1][0] = __builtin_amdgcn_mfma_f32_16x16x32_f16(fi1.v, fr0.v, aIm[1][0], 0, 0, 0);
            aIm[1][1] = __builtin_amdgcn_mfma_f32_16x16x32_f16(fr1.v, fi1.v, aIm[1][1], 0, 0, 0);
            aIm[1][1] = __builtin_amdgcn_mfma_f32_16x16x32_f16(fi1.v, fr1.v, aIm[1][1], 0, 0, 0);
        }
    }
    __syncthreads();
    float* rbuf = (float*)lds;
    int dcol = lane & 15, rrow = lane >> 4;
    #pragma unroll
    for (int i = 0; i < 2; ++i)
        #pragma unroll
        for (int j = 0; j < 2; ++j)
            #pragma unroll
            for (int r = 0; r < 4; ++r){
                int c = (i << 4) + (rrow << 2) + r;
                int d = (j << 4) + dcol;
                rbuf[wave*2048 + ((c << 5) + d)*2    ] = aRe[i][j][r];
                rbuf[wave*2048 + ((c << 5) + d)*2 + 1] = aIm[i][j][r];
            }
    __syncthreads();
    float* gp = Gpart + (size_t)blockIdx.x * 2048;
    for (int idx = t; idx < 2048; idx += 256)
        gp[idx] = rbuf[idx] + rbuf[2048 + idx] + rbuf[4096 + idx] + rbuf[6144 + idx];
}

// ---------- K2b: reduce 32 k-split partials per bh ----------
__global__ __launch_bounds__(256) void k_gram_red(const float* __restrict__ Gpart, float* __restrict__ G){
    int bh = blockIdx.x >> 3;
    int q  = ((blockIdx.x & 7) << 8) + threadIdx.x;
    const float* gp = Gpart + (size_t)bh * 32 * 2048 + q;
    float s = 0.f;
    #pragma unroll 8
    for (int p = 0; p < 32; ++p) s += gp[(size_t)p * 2048];
    G[(size_t)bh * 2048 + q] = s;
}

// ---------- K3: normalize, temperature, complex softmax, fold IF32 * (1/524288) ----------
__global__ __launch_bounds__(256) void k_attn(const float* __restrict__ G, const float* __restrict__ norm2,
                                              const float* __restrict__ temp, float* __restrict__ attn2){
    __shared__ float ar[32*33], ai[32*33];
    int bh = blockIdx.x, h = bh & 7, t = threadIdx.x;
    if (t < 32){
        float tv = temp[h];
        float nc = fmaxf(sqrtf(norm2[(bh<<5) + t]), 1e-12f);
        const float* gr = G + (size_t)bh*2048 + t*64;
        float mr = -1e30f, mi = -1e30f;
        for (int d = 0; d < 32; ++d){
            float nd = fmaxf(sqrtf(norm2[(bh<<5) + d]), 1e-12f);
            float s = tv / (nc * nd);
            float vr = gr[d*2] * s, vi = gr[d*2+1] * s;
            ar[t*33+d] = vr; ai[t*33+d] = vi;
            mr = fmaxf(mr, vr); mi = fmaxf(mi, vi);
        }
        float sr = 0.f, si = 0.f;
        for (int d = 0; d < 32; ++d){
            float er = __expf(ar[t*33+d] - mr), ei = __expf(ai[t*33+d] - mi);
            ar[t*33+d] = er; ai[t*33+d] = ei; sr += er; si += ei;
        }
        sr = 1.f/sr; si = 1.f/si;
        for (int d = 0; d < 32; ++d){ ar[t*33+d] *= sr; ai[t*33+d] *= si; }
    }
    __syncthreads();
    const float S = 1.f / 524288.f;
    for (int q = t; q < 1024; q += 256){
        int e = q >> 5, d = q & 31;
        float sr = 0.f, si = 0.f;
        for (int c = 0; c < 32; ++c){
            float sn, cs; sincos_rev((float)((e*c) & 31) * 0.03125f, sn, cs);
            float xr = ar[c*33+d], xi = ai[c*33+d];
            sr += cs*xr - sn*xi;
            si += cs*xi + sn*xr;
        }
        attn2[(size_t)bh*2048 + q*2]     = sr * S;
        attn2[(size_t)bh*2048 + q*2 + 1] = si * S;
    }
}

// ---------- K4: mix[e][n] = sum_d attn2[e][d] * X[d][n] via f16 MFMA ----------
__global__ __launch_bounds__(256) void k_mix(const unsigned* __restrict__ spR, const unsigned* __restrict__ spI,
                                             const float* __restrict__ attn2,
                                             unsigned* __restrict__ om){
    __shared__ unsigned lds[2*32*36];
    __shared__ float a2s[2048];
    int t = threadIdx.x, lane = t & 63, wave = t >> 6;
    int quad = lane >> 4, l15 = lane & 15;
    int bh = blockIdx.x >> 5;
    int n0 = (blockIdx.x & 31) << 9;
    size_t cbase2 = (size_t)bh * 32 * 8192;
    {
        const float4* s4 = (const float4*)(attn2 + (size_t)bh*2048);
        float4* d4 = (float4*)a2s;
        d4[t] = s4[t]; d4[t + 256] = s4[t + 256];
    }
    __syncthreads();
    FU16 Ar[2], Ai[2];
    #pragma unroll
    for (int et = 0; et < 2; ++et){
        int e = (et << 4) + l15;
        #pragma unroll
        for (int p = 0; p < 4; ++p){
            int d0 = (quad << 3) + (p << 1);
            Ar[et].u[p] = packh(a2s[(e*32 + d0)*2],     a2s[(e*32 + d0 + 1)*2]);
            Ai[et].u[p] = packh(a2s[(e*32 + d0)*2 + 1], a2s[(e*32 + d0 + 1)*2 + 1]);
        }
    }
    int sd = t >> 3, sc4 = (t & 7) << 2;
    for (int tile = 0; tile < 8; ++tile){
        int nb = n0 + (tile << 6);
        __syncthreads();
        {
            size_t g2 = cbase2 + (size_t)sd*8192 + (nb >> 1) + sc4;
            *(uint4*)&lds[sd*36 + sc4]         = *(const uint4*)&spR[g2];
            *(uint4*)&lds[32*36 + sd*36 + sc4] = *(const uint4*)&spI[g2];
        }
        __syncthreads();
        int colb = (wave << 4) + l15;
        int cb2 = colb >> 1; bool codd = colb & 1;
        FU16 Xr, Xi, Xn;
        #pragma unroll
        for (int p = 0; p < 4; ++p){
            int d0 = (quad << 3) + (p << 1);
            unsigned e0 = lds[d0*36 + cb2], e1 = lds[(d0+1)*36 + cb2];
            Xr.u[p] = codd ? ((e0 >> 16) | (e1 & 0xFFFF0000u)) : ((e0 & 0xFFFFu) | (e1 << 16));
            e0 = lds[32*36 + d0*36 + cb2]; e1 = lds[32*36 + (d0+1)*36 + cb2];
            Xi.u[p] = codd ? ((e0 >> 16) | (e1 & 0xFFFF0000u)) : ((e0 & 0xFFFFu) | (e1 << 16));
            Xn.u[p] = Xi.u[p] ^ 0x80008000u;
        }
        #pragma unroll
        for (int et = 0; et < 2; ++et){
            f32x4 ar = (f32x4){0,0,0,0}, ai = (f32x4){0,0,0,0};
            ar = __builtin_amdgcn_mfma_f32_16x16x32_f16(Ar[et].v, Xr.v, ar, 0, 0, 0);
            ar = __builtin_amdgcn_mfma_f32_16x16x32_f16(Ai[et].v, Xn.v, ar, 0, 0, 0);
            ai = __builtin_amdgcn_mfma_f32_16x16x32_f16(Ar[et].v, Xi.v, ai, 0, 0, 0);
            ai = __builtin_amdgcn_mfma_f32_16x16x32_f16(Ai[et].v, Xr.v, ai, 0, 0, 0);
            #pragma unroll
            for (int r = 0; r < 4; ++r){
                int e = (et << 4) + (quad << 2) + r;
                om[cbase2*2 + (size_t)e*NFFT + nb + colb] = packh(ar[r], ai[r]);
            }
        }
    }
}

// ---------- K5: fused 16384-pt inverse FFT + abs per row; fp16-packed complex in, f16 out (packed pairs) ----------
__global__ __launch_bounds__(1024, 8) void k_ifft_n(const unsigned* __restrict__ in, unsigned* __restrict__ outp){
    __shared__ unsigned sp[128*129];
    int lane = threadIdx.x & 63, wave = threadIdx.x >> 6;
    size_t rb = (size_t)blockIdx.x * NFFT;
    TwI tw; make_twi(tw);
    #pragma unroll 2
    for (int it = 0; it < 8; ++it){
        int jw = (wave << 3) + it;
        size_t base = rb + ((size_t)jw << 7);
        float a0, b0, a1, b1;
        unpackh(in[base + lane], a0, b0);
        unpackh(in[base + lane + 64], a1, b1);
        dit128t(tw, a0, b0, a1, b1);
        int kw = rev7(jw);
        float sn, cs;
        sincos_rev((float)(lane * kw) * 6.103515625e-05f, sn, cs);
        float r = a0*cs - b0*sn, i2 = a0*sn + b0*cs;
        sp[lane*129 + jw] = packh(r, i2);
        sincos_rev((float)((lane + 64) * kw) * 6.103515625e-05f, sn, cs);
        r = a1*cs - b1*sn; i2 = a1*sn + b1*cs;
        sp[(lane+64)*129 + jw] = packh(r, i2);
    }
    __syncthreads();
    float av0[8], av1[8];
    #pragma unroll
    for (int it = 0; it < 8; ++it){
        int pw = (wave << 3) + it;
        float a0, b0, a1, b1;
        unpackh(sp[pw*129 + lane],      a0, b0);
        unpackh(sp[pw*129 + lane + 64], a1, b1);
        dit128t(tw, a0, b0, a1, b1);
        av0[it] = sqrtf(a0*a0 + b0*b0);
        av1[it] = sqrtf(a1*a1 + b1*b1);
    }
    __syncthreads();
    // transpose via LDS at half width: u32 holds f16 pair of adjacent columns (pw, pw+1)
    #pragma unroll
    for (int p = 0; p < 4; ++p){
        sp[lane*65 + (wave << 2) + p]      = packh(av0[2*p], av0[2*p+1]);
        sp[(lane+64)*65 + (wave << 2) + p] = packh(av1[2*p], av1[2*p+1]);
    }
    __syncthreads();
    int row = threadIdx.x >> 3, cb = (threadIdx.x & 7) << 3;
    unsigned* ob = outp + ((size_t)blockIdx.x << 13) + row*64 + cb;
    const unsigned* s = &sp[row*65 + cb];
    *(uint4*)(ob)     = make_uint4(s[0], s[1], s[2], s[3]);
    *(uint4*)(ob + 4) = make_uint4(s[4], s[5], s[6], s[7]);
}

// ---------- K6: gating, IN-PLACE on fp16 half-planes ----------
__global__ __launch_bounds__(256) void k_gate(unsigned* spR, unsigned* spI,
                                              const float* __restrict__ w1, const float* __restrict__ b1,
                                              const float* __restrict__ bg, const float* __restrict__ bb_,
                                              const float* __restrict__ bm, const float* __restrict__ bv,
                                              const float* __restrict__ w2, const float* __restrict__ b2){
    __shared__ float w1T[256*17];
    __shared__ float w2s[256*16];
    __shared__ float yred[256*17];
    int t = threadIdx.x, g = t >> 6, col = t & 63;
    #pragma unroll
    for (int i = 0; i < 16; ++i) w1T[t*17 + i] = w1[i*256 + t];
    {
        const float4* s4 = (const float4*)w2; float4* d4 = (float4*)w2s;
        #pragma unroll
        for (int i = 0; i < 4; ++i) d4[i*256 + t] = s4[i*256 + t];
    }
    __syncthreads();
    int b = blockIdx.x >> 8;
    int n = ((blockIdx.x & 255) << 6) + col;
    int odd = n & 1;
    size_t base2 = (((size_t)b << 8) << 13) + (n >> 1);
    float y[16];
    #pragma unroll
    for (int r = 0; r < 16; ++r) y[r] = 0.f;
    for (int c = g << 6; c < (g << 6) + 64; ++c){
        float lo, hi; unpackh(spR[base2 + ((size_t)c << 13)], lo, hi);
        float xr = odd ? hi : lo;
        #pragma unroll
        for (int r = 0; r < 16; ++r) y[r] += w1T[c*17 + r] * xr;
    }
    #pragma unroll
    for (int r = 0; r < 16; ++r) yred[t*17 + r] = y[r];
    __syncthreads();
    #pragma unroll
    for (int r = 0; r < 16; ++r){
        float v = yred[col*17 + r] + yred[(col+64)*17 + r]
                + yred[(col+128)*17 + r] + yred[(col+192)*17 + r] + b1[r];
        v = (v - bm[r]) * rsqrtf(bv[r] + 1e-5f) * bg[r] + bb_[r];
        y[r] = fmaxf(v, 0.f);
    }
    for (int o = g << 6; o < (g << 6) + 64; ++o){
        float s = b2[o];
        #pragma unroll
        for (int r = 0; r < 16; ++r) s += w2s[o*16 + r] * y[r];
        float gg = 1.f / (1.f + __expf(-s)) * 6.103515625e-05f;   // sigmoid * 1/16384
        float ggN = __shfl_xor(gg, 1, 64);
        size_t mi = base2 + ((size_t)o << 13);
        if (!odd){
            float lo, hi; unpackh(spR[mi], lo, hi);
            spR[mi] = packh(gg*lo, ggN*hi);
        } else {
            float lo, hi; unpackh(spI[mi], lo, hi);
            spI[mi] = packh(ggN*lo, gg*hi);
        }
    }
}

// ---------- K7: fused ifft2 per image + abs -> f16 (packed pairs) into Cat1 ----------
__global__ __launch_bounds__(1024, 8) void k_ifft2_gate(const unsigned* __restrict__ spR,
                                                        const unsigned* __restrict__ spI,
                                                        unsigned* __restrict__ outp){
    __shared__ unsigned sp[128*129];
    int lane = threadIdx.x & 63, wave = threadIdx.x >> 6;
    TwI tw; make_twi(tw);
    size_t ib = (size_t)blockIdx.x * NFFT;
    #pragma unroll 2
    for (int it = 0; it < 8; ++it){
        int jw = (wave << 3) + it;
        size_t m = (ib + ((size_t)jw << 7)) >> 1;
        int k = lane >> 1; bool od = lane & 1;
        float lo, hi, a0, b0, a1, b1;
        unpackh(spR[m + k], lo, hi);      a0 = od ? hi : lo;
        unpackh(spI[m + k], lo, hi);      b0 = od ? hi : lo;
        unpackh(spR[m + 32 + k], lo, hi); a1 = od ? hi : lo;
        unpackh(spI[m + 32 + k], lo, hi); b1 = od ? hi : lo;
        dit128t(tw, a0, b0, a1, b1);
        sp[lane*129 + jw]      = packh(a0, b0);
        sp[(lane+64)*129 + jw] = packh(a1, b1);
    }
    __syncthreads();
    #pragma unroll 2
    for (int it = 0; it < 8; ++it){
        int ph = (wave << 3) + it;
        float a0, b0, a1, b1;
        unpackh(sp[ph*129 + lane],      a0, b0);
        unpackh(sp[ph*129 + lane + 64], a1, b1);
        dit128t(tw, a0, b0, a1, b1);
        float v0 = sqrtf(a0*a0 + b0*b0), v1 = sqrtf(a1*a1 + b1*b1);
        float p0 = __shfl_xor(v0, 1, 64), p1 = __shfl_xor(v1, 1, 64);
        if (!(lane & 1)){
            size_t o2 = ((size_t)blockIdx.x << 13) + (ph << 6);
            outp[o2 + (lane >> 1)]      = packh(v0, p0);
            outp[o2 + 32 + (lane >> 1)] = packh(v1, p1);
        }
    }
}

// ---------- K7b: pack pw into f16 pairs (along k) ----------
__global__ __launch_bounds__(256) void k_pw_cvt(const float* __restrict__ pw, unsigned* __restrict__ pwp){
    int i = (blockIdx.x << 10) + (threadIdx.x << 2);
    float4 v = *(const float4*)(pw + i);
    uint2 o;
    o.x = packh(v.x, v.y); o.y = packh(v.z, v.w);
    *(uint2*)(pwp + (i >> 1)) = o;
}

// ---------- K8: projection via f16 MFMA, single product per fragment ----------
__global__ __launch_bounds__(256) void k_proj(const unsigned* __restrict__ cat0, const unsigned* __restrict__ cat1,
                                              const unsigned* __restrict__ pwp, float* __restrict__ out){
    __shared__ unsigned As[128*17];   // [o][k2] f16 pairs along k, stride 17
    __shared__ unsigned Bs[32*65];    // [k][n2] f16 pairs along n, stride 65
    int t = threadIdx.x, lane = t & 63, wave = t >> 6;
    int quad = lane >> 4, l15 = lane & 15;
    int b  = blockIdx.x >> 8;
    int mo = (blockIdx.x >> 7) & 1;
    int nt = blockIdx.x & 127;
    int n0 = nt << 7;
    int n0_2 = nt << 6;
    int wr = (wave >> 1) << 6;
    int wc = (wave & 1) << 6;

    f32x4 acc[4][4];
    #pragma unroll
    for (int i = 0; i < 4; ++i)
        #pragma unroll
        for (int j = 0; j < 4; ++j) acc[i][j] = (f32x4){0.f,0.f,0.f,0.f};

    int ao = t >> 1, ak = (t & 1) << 3;
    int bk = t >> 3, bn8 = (t & 7) << 3;
    int par = l15 & 1;

    for (int ks = 0; ks < 16; ++ks){
        __syncthreads();
        {
            const unsigned* ap = pwp + (size_t)((mo << 7) + ao)*256 + (ks << 4) + ak;
            #pragma unroll
            for (int i = 0; i < 8; ++i) As[ao*17 + ak + i] = ap[i];
        }
        {
            int q = (ks << 5) + bk;
            const unsigned* srow = (q < 256) ? (cat0 + (size_t)((b << 8) + q) * 8192)
                                             : (cat1 + (size_t)((b << 8) + q - 256) * 8192);
            const unsigned* sp_ = srow + n0_2 + bn8;
            *(uint4*)&Bs[bk*65 + bn8]     = *(const uint4*)sp_;
            *(uint4*)&Bs[bk*65 + bn8 + 4] = *(const uint4*)(sp_ + 4);
        }
        __syncthreads();
        FU16 Af[4], Bf[4];
        #pragma unroll
        for (int mi = 0; mi < 4; ++mi){
            const unsigned* ap = &As[(wr + (mi << 4) + l15)*17 + (quad << 2)];
            #pragma unroll
            for (int p = 0; p < 4; ++p) Af[mi].u[p] = ap[p];
        }
        #pragma unroll
        for (int ni = 0; ni < 4; ++ni){
            int n2 = (wc + (ni << 4) + l15) >> 1;
            #pragma unroll
            for (int p = 0; p < 4; ++p){
                unsigned e0 = Bs[((quad << 3) + 2*p)*65 + n2];
                unsigned e1 = Bs[((quad << 3) + 2*p + 1)*65 + n2];
                Bf[ni].u[p] = par ? ((e0 >> 16) | (e1 & 0xFFFF0000u))
                                  : ((e0 & 0xFFFFu) | (e1 << 16));
            }
        }
        #pragma unroll
        for (int mi = 0; mi < 4; ++mi)
            #pragma unroll
            for (int ni = 0; ni < 4; ++ni)
                acc[mi][ni] = __builtin_amdgcn_mfma_f32_16x16x32_f16(Af[mi].v, Bf[ni].v, acc[mi][ni], 0, 0, 0);
    }
    size_t obase = (size_t)((b << 8) + (mo << 7));
    #pragma unroll
    for (int mi = 0; mi < 4; ++mi)
        #pragma unroll
        for (int ni = 0; ni < 4; ++ni){
            int o_ = wr + (mi << 4) + (quad << 2);
            int n_ = n0 + wc + (ni << 4) + l15;
            float* op = out + (obase + o_)*NFFT + n_;
            #pragma unroll
            for (int r = 0; r < 4; ++r) op[(size_t)r*NFFT] = acc[mi][ni][r];
        }
}

// ---------- host ----------
extern "C" void kernel_launch(void* const* d_in, const int* in_sizes, int n_in,
                              void* d_out, int out_size, void* d_ws, size_t ws_size,
                              hipStream_t stream) {
    const float* x    = (const float*)d_in[0];
    const float* temp = (const float*)d_in[1];
    const float* w1   = (const float*)d_in[2];
    const float* b1   = (const float*)d_in[3];
    const float* bg   = (const float*)d_in[4];
    const float* bb_  = (const float*)d_in[5];
    const float* bm   = (const float*)d_in[6];
    const float* bv   = (const float*)d_in[7];
    const float* w2   = (const float*)d_in[8];
    const float* b2   = (const float*)d_in[9];
    const float* pw   = (const float*)d_in[10];
    float* out = (float*)d_out;

    float* ws = (float*)d_ws;
    unsigned* SpecR = (unsigned*)ws;             // fp16 re half-plane, NP/2 u32
    unsigned* SpecI = SpecR + (NP >> 1);         // fp16 im half-plane
    unsigned* Ecat  = (unsigned*)(ws + NP);      // Gpart scratch -> mix out (fp16 cplx), read by ifft_n
    unsigned* Cat0  = (unsigned*)(ws + 2*NP);    // ifft_n out, f16 pairs (8.4M u32)
    unsigned* Cat1  = Cat0 + 8388608;            // ifft2_gate out, f16 pairs (8.4M u32)
    float* norm2 = ws + 3*NP;                    // 1024
    float* G     = norm2 + 1024;                 // 65536
    float* attn2 = G + 65536;                    // 65536
    unsigned* pwpack = (unsigned*)(attn2 + 65536);  // 65536 u32 (f16 pairs)
    float* Gpart = (float*)Ecat;                 // 8 MB scratch, dead until k_mix

    size_t need = (3*NP + 1024 + 65536 + 65536 + 131072) * sizeof(float);
    if (ws_size < need) return;

    k_pw_cvt<<<128, 256, 0, stream>>>(pw, pwpack);
    k_fft2_fwd<<<1024, 1024, 0, stream>>>(x, SpecR, SpecI, norm2);
    k_gram<<<1024, 256, 0, stream>>>(SpecR, SpecI, Gpart);
    k_gram_red<<<256, 256, 0, stream>>>(Gpart, G);
    k_attn<<<32, 256, 0, stream>>>(G, norm2, temp, attn2);
    k_mix<<<1024, 256, 0, stream>>>(SpecR, SpecI, attn2, Ecat);
    k_ifft_n<<<1024, 1024, 0, stream>>>(Ecat, Cat0);
    k_gate<<<1024, 256, 0, stream>>>(SpecR, SpecI, w1, b1, bg, bb_, bm, bv, w2, b2);
    k_ifft2_gate<<<1024, 1024, 0, stream>>>(SpecR, SpecI, Cat1);
    k_proj<<<1024, 256, 0, stream>>>(Cat0, Cat1, pwpack, out);
    (void)in_sizes; (void)n_in; (void)out_size; (void)ws_size;
}